// Round 7
// baseline (497.901 us; speedup 1.0000x reference)
//
#include <hip/hip_runtime.h>
#include <hip/hip_bf16.h>
#include <math.h>

using bf16 = __hip_bfloat16;
typedef __attribute__((ext_vector_type(8))) short short8;
typedef __attribute__((ext_vector_type(4))) float f32x4;
typedef unsigned int u32;

// ---------------- problem constants ----------------
constexpr int BB    = 4;
constexpr int Hh    = 112;
constexpr int Ww    = 112;
constexpr int C     = 256;
constexpr int L     = Hh * Ww;        // 12544
constexpr int HEADS = 8;
constexpr int WS    = 7;
constexpr int SHIFT = 3;
constexpr int HID   = 1024;
constexpr int HD    = 32;
constexpr int NWIN  = 49;
constexpr int NW    = 256;
constexpr int BT    = BB * NW;        // 1024 windows
constexpr int M     = BT * NWIN;      // 50176 tokens
constexpr float SCALE = 0.17677669529663687f;
constexpr float EPS   = 1e-5f;

// window-token r -> natural token index. Same map for gather and scatter.
__device__ __forceinline__ int src_row_idx(int r) {
    int b_ = r / NWIN;
    int n  = r - b_ * NWIN;
    int b  = b_ >> 8;
    int w  = b_ & 255;
    int wh = w >> 4, ww = w & 15;
    int i  = n / WS, j = n - i * WS;
    int hp = wh * WS + i, wp = ww * WS + j;
    int h  = hp + SHIFT; if (h >= Hh) h -= Hh;
    int wc = wp + SHIFT; if (wc >= Ww) wc -= Ww;
    return b * L + h * Ww + wc;
}

__device__ __forceinline__ float bf2f(short s) {
    u32 u = ((u32)(unsigned short)s) << 16;
    float f; __builtin_memcpy(&f, &u, 4); return f;
}

#define GL2LDS(g, l) __builtin_amdgcn_global_load_lds( \
    (const __attribute__((address_space(1))) u32*)(const void*)(g), \
    (__attribute__((address_space(3))) u32*)(void*)(l), 16, 0, 0)

// ---------------- per-token LN stats (mean, rstd) ----------------
__global__ __launch_bounds__(256)
void stats_kernel(const float* __restrict__ x, float* __restrict__ stats) {
    int wave = threadIdx.x >> 6, lane = threadIdx.x & 63;
    int tok  = blockIdx.x * 4 + wave;
    const float4 v = *(const float4*)&x[(size_t)tok * C + lane * 4];
    float s  = v.x + v.y + v.z + v.w;
    float s2 = v.x*v.x + v.y*v.y + v.z*v.z + v.w*v.w;
    #pragma unroll
    for (int o = 32; o > 0; o >>= 1) {
        s  += __shfl_down(s, o);
        s2 += __shfl_down(s2, o);
    }
    if (lane == 0) {
        float m   = s * (1.0f / C);
        float var = s2 * (1.0f / C) - m * m;
        stats[tok * 2]     = m;
        stats[tok * 2 + 1] = rsqrtf(var + EPS);
    }
}

// ---------------- f32 -> bf16 weight convert ----------------
__global__ __launch_bounds__(256)
void cvt_w(const float* __restrict__ in, bf16* __restrict__ o, int n4) {
    int i = blockIdx.x * 256 + threadIdx.x;
    if (i >= n4) return;
    float4 v = *(const float4*)&in[(size_t)i * 4];
    bf16 t4[4] = {__float2bfloat16(v.x), __float2bfloat16(v.y),
                  __float2bfloat16(v.z), __float2bfloat16(v.w)};
    *(uint2*)&o[(size_t)i * 4] = *(const uint2*)t4;
}

// ---------------- vote-embed MLP (one wave per token) ----------------
__global__ __launch_bounds__(256)
void vemb_kernel(const float* __restrict__ vote,
                 const float* __restrict__ w1, const float* __restrict__ b1,
                 const float* __restrict__ w2, const float* __restrict__ b2,
                 bf16* __restrict__ vemb) {
    int r = blockIdx.x * 4 + (threadIdx.x >> 6);
    int lane = threadIdx.x & 63;
    int srow = src_row_idx(r);
    float v0 = vote[(size_t)srow * 3];
    float v1 = vote[(size_t)srow * 3 + 1];
    float v2c = vote[(size_t)srow * 3 + 2];
    float hid[16];
    #pragma unroll
    for (int o = 0; o < 16; ++o)
        hid[o] = fmaxf(w1[o*3]*v0 + w1[o*3+1]*v1 + w1[o*3+2]*v2c + b1[o], 0.f);
    bf16 t4[4];
    #pragma unroll
    for (int j = 0; j < 4; ++j) {
        int c = lane * 4 + j;
        float a = b2[c];
        #pragma unroll
        for (int o = 0; o < 16; ++o) a += hid[o] * w2[c * 16 + o];
        t4[j] = __float2bfloat16(a);
    }
    *(uint2*)&vemb[(size_t)r * C + lane * 4] = *(const uint2*)t4;
}

// ---------------- MFMA GEMM, 2-phase pipelined K-loop ----------
// 128x128 tile, BK=64, 4 waves x 64x64 output (4x4 16x16x32 frags).
// LDS: A single buf [128][128B], B double buf 2x[128][128B], XOR swizzle
// byte ^= ((row&7)<<4). Staging for step t+1 is ISSUED before the MFMA
// phase of step t (loads in flight across compute; barrier drains after).
enum { MODE_QKV = 0, MODE_PROJ = 1, MODE_FC1 = 2, MODE_FC2 = 3 };

template <int MODE>
__global__ __launch_bounds__(256)
void mfma_gemm(const void* __restrict__ Asrc_, const bf16* __restrict__ Wb,
               const float* __restrict__ bias, const float* __restrict__ stats,
               const float* __restrict__ gamma, const float* __restrict__ beta,
               const bf16* __restrict__ vemb, const float* __restrict__ resid,
               void* __restrict__ outp) {
    constexpr int  K  = (MODE == MODE_FC2) ? 1024 : 256;
    constexpr int  T  = K / 64;
    constexpr bool LN = (MODE == MODE_QKV) || (MODE == MODE_FC1);
    __shared__ __align__(16) char ldsA[16384];
    __shared__ __align__(16) char ldsBb[2][16384];
    __shared__ float ldsG[256], ldsBt[256];     // gamma/beta (LN modes, K=256)

    const int tid  = threadIdx.x;
    const int lane = tid & 63;
    const int wid  = tid >> 6;
    const int wr   = wid >> 1, wc = wid & 1;
    const int lrow = lane & 15, lk = lane >> 4;
    const int mBase = blockIdx.x * 128, nBase = blockIdx.y * 128;

    const int s_sub = tid >> 3;                       // 0..31 row-in-rep
    const int chunk = tid & 7;                        // 16B chunk in row
    const int s_dst = (chunk * 16) ^ ((s_sub & 7) << 4);
    const char* bSrc = (const char*)(Wb + (size_t)(nBase + s_sub) * K) + s_dst;

    int arow[4]; float amean[4], arstd[4];
    #pragma unroll
    for (int r = 0; r < 4; ++r) {
        int row  = mBase + r * 32 + s_sub;
        int srow = (MODE == MODE_QKV) ? src_row_idx(row) : row;
        arow[r] = srow;
        if constexpr (LN) {
            amean[r] = stats[srow * 2];
            arstd[r] = stats[srow * 2 + 1];
        }
    }

    float4 sa0[4], sa1[4];   // A stage regs (LN modes, f32)
    short8 sab[4];           // A stage regs (bf16 modes)

    auto loadA = [&](int tt) {
        #pragma unroll
        for (int r = 0; r < 4; ++r) {
            if constexpr (LN) {
                const float* ap = (const float*)Asrc_ + (size_t)arow[r] * K + tt * 64 + chunk * 8;
                sa0[r] = *(const float4*)ap;
                sa1[r] = *(const float4*)(ap + 4);
            } else {
                sab[r] = *(const short8*)((const bf16*)Asrc_ + (size_t)arow[r] * K + tt * 64 + chunk * 8);
            }
        }
    };
    auto writeA = [&](int tt) {
        #pragma unroll
        for (int r = 0; r < 4; ++r) {
            if constexpr (LN) {
                const int kk = tt * 64 + chunk * 8;
                float m = amean[r], sd = arstd[r];
                float av[8] = {sa0[r].x, sa0[r].y, sa0[r].z, sa0[r].w,
                               sa1[r].x, sa1[r].y, sa1[r].z, sa1[r].w};
                bf16 tb[8];
                #pragma unroll
                for (int j = 0; j < 8; ++j)
                    tb[j] = __float2bfloat16((av[j] - m) * sd * ldsG[kk + j] + ldsBt[kk + j]);
                *(short8*)(ldsA + (r * 32 + s_sub) * 128 + s_dst) = *(const short8*)tb;
            } else {
                *(short8*)(ldsA + (r * 32 + s_sub) * 128 + s_dst) = sab[r];
            }
        }
    };

    f32x4 acc[4][4] = {};

    // prologue: stage step 0
    loadA(0);
    #pragma unroll
    for (int r = 0; r < 4; ++r)
        GL2LDS(bSrc + (size_t)r * 64 * K, ldsBb[0] + r * 4096 + wid * 1024);
    if constexpr (LN) { ldsG[tid] = gamma[tid]; ldsBt[tid] = beta[tid]; }
    __syncthreads();          // drains A-reg loads + B(0) DMA; ldsG visible
    writeA(0);
    __syncthreads();          // A(0) visible

    const int sw = (lrow & 7) << 4;
    #pragma unroll
    for (int t = 0; t < T; ++t) {
        if (t + 1 < T) {      // issue next-step staging BEFORE compute
            #pragma unroll
            for (int r = 0; r < 4; ++r)
                GL2LDS(bSrc + (size_t)r * 64 * K + (size_t)(t + 1) * 128,
                       ldsBb[(t + 1) & 1] + r * 4096 + wid * 1024);
            loadA(t + 1);
        }
        const char* curB = ldsBb[t & 1];
        #pragma unroll
        for (int ks = 0; ks < 2; ++ks) {
            const int kbl = (ks * 64 + lk * 16) ^ sw;
            short8 af[4], bfr[4];
            #pragma unroll
            for (int q = 0; q < 4; ++q) {
                af[q]  = *(const short8*)(ldsA + (wr * 64 + q * 16 + lrow) * 128 + kbl);
                bfr[q] = *(const short8*)(curB + (wc * 64 + q * 16 + lrow) * 128 + kbl);
            }
            #pragma unroll
            for (int mi = 0; mi < 4; ++mi)
                #pragma unroll
                for (int ni = 0; ni < 4; ++ni)
                    acc[mi][ni] = __builtin_amdgcn_mfma_f32_16x16x32_bf16(
                        af[mi], bfr[ni], acc[mi][ni], 0, 0, 0);
        }
        if (t + 1 < T) {
            __syncthreads();  // drains B(t+1) DMA + A regs; all ldsA reads done
            writeA(t + 1);
            __syncthreads();  // A(t+1) visible
        }
    }

    // epilogue: lane holds D[(lane>>4)*4+i][lane&15] of each 16x16 frag
    const int cB = nBase + wc * 64 + lrow;
    const int rB = mBase + wr * 64 + lk * 4;
    #pragma unroll
    for (int ni = 0; ni < 4; ++ni) {
        const int c = cB + ni * 16;
        const float bs = bias[c];
        #pragma unroll
        for (int mi = 0; mi < 4; ++mi) {
            #pragma unroll
            for (int i = 0; i < 4; ++i) {
                const int r = rB + mi * 16 + i;
                float v = acc[mi][ni][i] + bs;
                if constexpr (MODE == MODE_QKV) {
                    float ve = __bfloat162float(vemb[(size_t)r * 256 + (c & 255)]);
                    v += (c >= 512) ? 2.f * ve : ve;
                    ((bf16*)outp)[(size_t)r * 768 + c] = __float2bfloat16(v);
                } else if constexpr (MODE == MODE_PROJ) {
                    int dst = src_row_idx(r);
                    ((float*)outp)[(size_t)dst * 256 + c] =
                        resid[(size_t)dst * 256 + c] + v;
                } else if constexpr (MODE == MODE_FC1) {
                    float gl = 0.5f * v * (1.f + erff(v * 0.70710678118f));
                    ((bf16*)outp)[(size_t)r * 1024 + c] = __float2bfloat16(gl);
                } else {
                    ((float*)outp)[(size_t)r * 256 + c] =
                        resid[(size_t)r * 256 + c] + v;
                }
            }
        }
    }
}

// ---------------- per-window attention: MFMA + RPE dedup ----------------
__global__ __launch_bounds__(256)
void attn_kernel(const bf16* __restrict__ qkv, const float* __restrict__ polar,
                 const float* __restrict__ rw1, const float* __restrict__ rb1,
                 const float* __restrict__ rw2, const float* __restrict__ rb2,
                 const float* __restrict__ tau, const float* __restrict__ mask,
                 bf16* __restrict__ outp) {
    const int w  = blockIdx.x;
    const int wl = w & 255;
    const int t  = threadIdx.x;
    const int lane = t & 63, wid = t >> 6;
    const int l15 = lane & 15, q4 = lane >> 4;
    const size_t wbase = (size_t)w * NWIN;

    __shared__ float pwx[NWIN], pwy[NWIN];
    __shared__ float rqn[8][64], rkn[8][64];
    __shared__ float cw1s[32], cb1s[16], cw2s[8][16], rb2s[8], scts[8];
    __shared__ bf16  rpem[4][2401];
    __shared__ short P_lds[64][72];
    __shared__ short VT[32][72];

    for (int i = t; i < 32 * 72; i += 256) ((short*)VT)[i] = 0;

    for (int u = t; u < 98; u += 256) {
        int n = u >> 1, cix = u & 1;
        int srow = src_row_idx(w * NWIN + n);
        float v = polar[(size_t)srow * 2 + cix];
        if (cix) pwy[n] = v; else pwx[n] = v;
    }
    if (t < 128) cw2s[t >> 4][t & 15] = rw2[t];
    else if (t < 160) cw1s[t - 128] = rw1[t - 128];
    else if (t < 176) cb1s[t - 160] = rb1[t - 160];
    else if (t < 184) rb2s[t - 176] = rb2[t - 176];
    else if (t < 192) scts[t - 184] = SCALE / fmaxf(tau[t - 184], 0.01f);

    for (int idx = t; idx < 8 * NWIN; idx += 256) {
        int h = idx / NWIN, n = idx - h * NWIN;
        const bf16* qp = qkv + (wbase + n) * 768 + h * 32;
        float sq = 0, sk = 0;
        #pragma unroll
        for (int c = 0; c < 4; ++c) {
            short8 qv = *(const short8*)(qp + c * 8);
            short8 kv = *(const short8*)(qp + 256 + c * 8);
            #pragma unroll
            for (int j = 0; j < 8; ++j) {
                float qf = bf2f(qv[j]); sq += qf * qf;
                float kf = bf2f(kv[j]); sk += kf * kf;
            }
        }
        rqn[h][n] = rsqrtf(sq);
        rkn[h][n] = rsqrtf(sk);
    }

    for (int g = 0; g < 2; ++g) {
        __syncthreads();
        for (int e = t; e < NWIN * NWIN; e += 256) {
            int n = e / NWIN, m = e - n * NWIN;
            float dx = pwx[n] - pwx[m], dy = pwy[n] - pwy[m];
            float hid[16];
            #pragma unroll
            for (int o = 0; o < 16; ++o)
                hid[o] = fmaxf(fmaf(cw1s[2*o], dx, fmaf(cw1s[2*o+1], dy, cb1s[o])), 0.f);
            float mv = mask[(size_t)wl * NWIN * NWIN + e];
            #pragma unroll
            for (int hh = 0; hh < 4; ++hh) {
                int h = 4 * g + hh;
                float a = rb2s[h] + mv;
                #pragma unroll
                for (int o = 0; o < 16; ++o) a = fmaf(hid[o], cw2s[h][o], a);
                rpem[hh][e] = __float2bfloat16(a);
            }
        }

        for (int hh = 0; hh < 4; ++hh) {
            const int h = 4 * g + hh;
            __syncthreads();

            {
                int n = t >> 2, ck = t & 3;
                if (n < NWIN) {
                    short8 vv8 = *(const short8*)(qkv + (wbase + n) * 768 + 512 + h * 32 + ck * 8);
                    #pragma unroll
                    for (int j = 0; j < 8; ++j) VT[ck * 8 + j][n] = vv8[j];
                }
            }

            short8 aq = {0,0,0,0,0,0,0,0};
            {
                int n = wid * 16 + l15;
                if (n < NWIN)
                    aq = *(const short8*)(qkv + (wbase + n) * 768 + h * 32 + q4 * 8);
            }
            short8 bk[4];
            #pragma unroll
            for (int c = 0; c < 4; ++c) {
                int m = c * 16 + l15;
                short8 z = {0,0,0,0,0,0,0,0};
                bk[c] = (m < NWIN)
                    ? *(const short8*)(qkv + (wbase + m) * 768 + 256 + h * 32 + q4 * 8)
                    : z;
            }
            f32x4 s[4] = {};
            #pragma unroll
            for (int c = 0; c < 4; ++c)
                s[c] = __builtin_amdgcn_mfma_f32_16x16x32_bf16(aq, bk[c], s[c], 0, 0, 0);

            const float sct = scts[h];
            float vv[4][4];
            #pragma unroll
            for (int c = 0; c < 4; ++c) {
                int m = c * 16 + l15;
                #pragma unroll
                for (int i = 0; i < 4; ++i) {
                    int n = wid * 16 + q4 * 4 + i;
                    float val = -1e30f;
                    if (n < NWIN && m < NWIN) {
                        float rr = fminf(rqn[h][n] * rkn[h][m], 1e6f);
                        val = s[c][i] * sct * rr + bf2f(*(short*)&rpem[hh][n * NWIN + m]);
                    }
                    vv[c][i] = val;
                }
            }

            #pragma unroll
            for (int i = 0; i < 4; ++i) {
                float mx = fmaxf(fmaxf(vv[0][i], vv[1][i]), fmaxf(vv[2][i], vv[3][i]));
                #pragma unroll
                for (int d = 1; d < 16; d <<= 1) mx = fmaxf(mx, __shfl_xor(mx, d));
                float sum = 0;
                #pragma unroll
                for (int c = 0; c < 4; ++c) {
                    float ev = __expf(vv[c][i] - mx);
                    vv[c][i] = ev; sum += ev;
                }
                #pragma unroll
                for (int d = 1; d < 16; d <<= 1) sum += __shfl_xor(sum, d);
                float inv = 1.0f / sum;
                #pragma unroll
                for (int c = 0; c < 4; ++c) vv[c][i] *= inv;
            }

            #pragma unroll
            for (int c = 0; c < 4; ++c)
                #pragma unroll
                for (int i = 0; i < 4; ++i) {
                    bf16 pb = __float2bfloat16(vv[c][i]);
                    short ps; __builtin_memcpy(&ps, &pb, 2);
                    P_lds[wid * 16 + q4 * 4 + i][c * 16 + l15] = ps;
                }

            __syncthreads();

            short8 pa[2];
            #pragma unroll
            for (int ks = 0; ks < 2; ++ks)
                pa[ks] = *(const short8*)&P_lds[wid * 16 + l15][ks * 32 + q4 * 8];
            f32x4 o[2] = {};
            #pragma unroll
            for (int ct = 0; ct < 2; ++ct) {
                #pragma unroll
                for (int ks = 0; ks < 2; ++ks) {
                    short8 vb = *(const short8*)&VT[ct * 16 + l15][ks * 32 + q4 * 8];
                    o[ct] = __builtin_amdgcn_mfma_f32_16x16x32_bf16(pa[ks], vb, o[ct], 0, 0, 0);
                }
            }
            #pragma unroll
            for (int ct = 0; ct < 2; ++ct)
                #pragma unroll
                for (int i = 0; i < 4; ++i) {
                    int n = wid * 16 + q4 * 4 + i;
                    if (n < NWIN)
                        outp[(wbase + n) * 256 + h * 32 + ct * 16 + l15] =
                            __float2bfloat16(o[ct][i]);
                }
        }
    }
}

// ---------------- launch ----------------
extern "C" void kernel_launch(void* const* d_in, const int* in_sizes, int n_in,
                              void* d_out, int out_size, void* d_ws, size_t ws_size,
                              hipStream_t stream) {
    const float* x     = (const float*)d_in[0];
    const float* mask  = (const float*)d_in[1];
    const float* polar = (const float*)d_in[2];
    const float* vote  = (const float*)d_in[3];
    const float* g1    = (const float*)d_in[4];
    const float* be1   = (const float*)d_in[5];
    const float* wqkv  = (const float*)d_in[6];
    const float* bqkv  = (const float*)d_in[7];
    const float* wproj = (const float*)d_in[8];
    const float* bproj = (const float*)d_in[9];
    const float* tau   = (const float*)d_in[10];
    const float* rw1   = (const float*)d_in[11];
    const float* rb1   = (const float*)d_in[12];
    const float* rw2   = (const float*)d_in[13];
    const float* rb2   = (const float*)d_in[14];
    const float* vw1   = (const float*)d_in[15];
    const float* vb1   = (const float*)d_in[16];
    const float* vw2   = (const float*)d_in[17];
    const float* vb2   = (const float*)d_in[18];
    const float* g2    = (const float*)d_in[19];
    const float* be2   = (const float*)d_in[20];
    const float* fc1w  = (const float*)d_in[21];
    const float* fc1b  = (const float*)d_in[22];
    const float* fc2w  = (const float*)d_in[23];
    const float* fc2b  = (const float*)d_in[24];
    float* out = (float*)d_out;

    // workspace (bytes), total ~105.1 MB (same plan as R4/R6)
    char* base = (char*)d_ws;
    bf16*  qkv     = (bf16*)base;
    bf16*  vemb    = (bf16*)(base + 77070336);
    bf16*  attnout = (bf16*)(base + 77070336);
    bf16*  hbuf    = (bf16*)base;
    bf16*  wqkvb   = (bf16*)(base + 102760448);
    bf16*  wprojb  = wqkvb + 768 * 256;
    bf16*  fc1wb   = wprojb + 256 * 256;
    bf16*  fc2wb   = fc1wb + 1024 * 256;
    float* stats1  = (float*)(base + 104333312);
    float* stats2  = stats1 + 2 * M;

    cvt_w<<<192, 256, 0, stream>>>(wqkv, wqkvb, 768*256/4);
    cvt_w<<<64,  256, 0, stream>>>(wproj, wprojb, 256*256/4);
    cvt_w<<<256, 256, 0, stream>>>(fc1w, fc1wb, 1024*256/4);
    cvt_w<<<256, 256, 0, stream>>>(fc2w, fc2wb, 256*1024/4);

    stats_kernel<<<M / 4, 256, 0, stream>>>(x, stats1);
    vemb_kernel<<<M / 4, 256, 0, stream>>>(vote, vw1, vb1, vw2, vb2, vemb);

    dim3 gqkv(M / 128, 768 / 128);
    mfma_gemm<MODE_QKV><<<gqkv, 256, 0, stream>>>(x, wqkvb, bqkv, stats1, g1, be1, vemb, nullptr, qkv);

    attn_kernel<<<BT, 256, 0, stream>>>(qkv, polar, rw1, rb1, rw2, rb2, tau, mask, attnout);

    dim3 gproj(M / 128, 256 / 128);
    mfma_gemm<MODE_PROJ><<<gproj, 256, 0, stream>>>(attnout, wprojb, bproj, nullptr, nullptr, nullptr, nullptr, x, out);

    stats_kernel<<<M / 4, 256, 0, stream>>>(out, stats2);

    dim3 gfc1(M / 128, 1024 / 128);
    mfma_gemm<MODE_FC1><<<gfc1, 256, 0, stream>>>(out, fc1wb, fc1b, stats2, g2, be2, nullptr, nullptr, hbuf);

    dim3 gfc2(M / 128, 256 / 128);
    mfma_gemm<MODE_FC2><<<gfc2, 256, 0, stream>>>(hbuf, fc2wb, fc2b, nullptr, nullptr, nullptr, nullptr, out, out);
}

// Round 8
// 482.618 us; speedup vs baseline: 1.0317x; 1.0317x over previous
//
#include <hip/hip_runtime.h>
#include <hip/hip_bf16.h>
#include <math.h>

using bf16 = __hip_bfloat16;
typedef __attribute__((ext_vector_type(8))) short short8;
typedef __attribute__((ext_vector_type(4))) float f32x4;
typedef unsigned int u32;

// ---------------- problem constants ----------------
constexpr int BB    = 4;
constexpr int Hh    = 112;
constexpr int Ww    = 112;
constexpr int C     = 256;
constexpr int L     = Hh * Ww;        // 12544
constexpr int HEADS = 8;
constexpr int WS    = 7;
constexpr int SHIFT = 3;
constexpr int HID   = 1024;
constexpr int HD    = 32;
constexpr int NWIN  = 49;
constexpr int NW    = 256;
constexpr int BT    = BB * NW;        // 1024 windows
constexpr int M     = BT * NWIN;      // 50176 tokens
constexpr float SCALE = 0.17677669529663687f;
constexpr float EPS   = 1e-5f;

// window-token r -> natural token index. Same map for gather and scatter.
__device__ __forceinline__ int src_row_idx(int r) {
    int b_ = r / NWIN;
    int n  = r - b_ * NWIN;
    int b  = b_ >> 8;
    int w  = b_ & 255;
    int wh = w >> 4, ww = w & 15;
    int i  = n / WS, j = n - i * WS;
    int hp = wh * WS + i, wp = ww * WS + j;
    int h  = hp + SHIFT; if (h >= Hh) h -= Hh;
    int wc = wp + SHIFT; if (wc >= Ww) wc -= Ww;
    return b * L + h * Ww + wc;
}

__device__ __forceinline__ float bf2f(short s) {
    u32 u = ((u32)(unsigned short)s) << 16;
    float f; __builtin_memcpy(&f, &u, 4); return f;
}

#define GL2LDS(g, l) __builtin_amdgcn_global_load_lds( \
    (const __attribute__((address_space(1))) u32*)(const void*)(g), \
    (__attribute__((address_space(3))) u32*)(void*)(l), 16, 0, 0)

// ---------------- per-token LN stats (mean, rstd) ----------------
__global__ __launch_bounds__(256)
void stats_kernel(const float* __restrict__ x, float* __restrict__ stats) {
    int wave = threadIdx.x >> 6, lane = threadIdx.x & 63;
    int tok  = blockIdx.x * 4 + wave;
    const float4 v = *(const float4*)&x[(size_t)tok * C + lane * 4];
    float s  = v.x + v.y + v.z + v.w;
    float s2 = v.x*v.x + v.y*v.y + v.z*v.z + v.w*v.w;
    #pragma unroll
    for (int o = 32; o > 0; o >>= 1) {
        s  += __shfl_down(s, o);
        s2 += __shfl_down(s2, o);
    }
    if (lane == 0) {
        float m   = s * (1.0f / C);
        float var = s2 * (1.0f / C) - m * m;
        stats[tok * 2]     = m;
        stats[tok * 2 + 1] = rsqrtf(var + EPS);
    }
}

// ---------------- f32 -> bf16 weight convert ----------------
__global__ __launch_bounds__(256)
void cvt_w(const float* __restrict__ in, bf16* __restrict__ o, int n4) {
    int i = blockIdx.x * 256 + threadIdx.x;
    if (i >= n4) return;
    float4 v = *(const float4*)&in[(size_t)i * 4];
    bf16 t4[4] = {__float2bfloat16(v.x), __float2bfloat16(v.y),
                  __float2bfloat16(v.z), __float2bfloat16(v.w)};
    *(uint2*)&o[(size_t)i * 4] = *(const uint2*)t4;
}

// ---------------- vote-embed MLP (one wave per token) ----------------
__global__ __launch_bounds__(256)
void vemb_kernel(const float* __restrict__ vote,
                 const float* __restrict__ w1, const float* __restrict__ b1,
                 const float* __restrict__ w2, const float* __restrict__ b2,
                 bf16* __restrict__ vemb) {
    int r = blockIdx.x * 4 + (threadIdx.x >> 6);
    int lane = threadIdx.x & 63;
    int srow = src_row_idx(r);
    float v0 = vote[(size_t)srow * 3];
    float v1 = vote[(size_t)srow * 3 + 1];
    float v2c = vote[(size_t)srow * 3 + 2];
    float hid[16];
    #pragma unroll
    for (int o = 0; o < 16; ++o)
        hid[o] = fmaxf(w1[o*3]*v0 + w1[o*3+1]*v1 + w1[o*3+2]*v2c + b1[o], 0.f);
    bf16 t4[4];
    #pragma unroll
    for (int j = 0; j < 4; ++j) {
        int c = lane * 4 + j;
        float a = b2[c];
        #pragma unroll
        for (int o = 0; o < 16; ++o) a += hid[o] * w2[c * 16 + o];
        t4[j] = __float2bfloat16(a);
    }
    *(uint2*)&vemb[(size_t)r * C + lane * 4] = *(const uint2*)t4;
}

// ---------------- MFMA GEMM (R6 structure + A-sharing 1D grid + store reorder)
// 128x128 tile, BK=64, 4 waves x 64x64. LDS [128][128B] XOR-swizzled.
// 1D grid: wgid = bx*NT + by -> the NT blocks sharing an A-panel are
// temporally adjacent (L2/L3 absorb A re-reads). Epilogue: ni innermost so
// the 4 stores covering one cache line are consecutive.
enum { MODE_QKV = 0, MODE_PROJ = 1, MODE_FC1 = 2, MODE_FC2 = 3 };

template <int MODE, int NT>
__global__ __launch_bounds__(256)
void mfma_gemm(const void* __restrict__ Asrc_, const bf16* __restrict__ Wb,
               const float* __restrict__ bias, const float* __restrict__ stats,
               const float* __restrict__ gamma, const float* __restrict__ beta,
               const bf16* __restrict__ vemb, const float* __restrict__ resid,
               void* __restrict__ outp) {
    constexpr int  K  = (MODE == MODE_FC2) ? 1024 : 256;
    constexpr bool LN = (MODE == MODE_QKV) || (MODE == MODE_FC1);
    __shared__ __align__(16) char lds[32768];
    char* ldsA = lds;
    char* ldsB = lds + 16384;

    const int tid  = threadIdx.x;
    const int lane = tid & 63;
    const int wid  = tid >> 6;
    const int wr   = wid >> 1, wc = wid & 1;
    const int lrow = lane & 15, lk = lane >> 4;
    const int bx = blockIdx.x / NT, by = blockIdx.x % NT;
    const int mBase = bx * 128, nBase = by * 128;

    const int s_sub = tid >> 3;
    const int chunk = tid & 7;
    const int s_dst = (chunk * 16) ^ ((s_sub & 7) << 4);
    const char* bSrc = (const char*)(Wb + (size_t)(nBase + s_sub) * K) + s_dst;

    int arow[4]; float amean[4], arstd[4];
    #pragma unroll
    for (int r = 0; r < 4; ++r) {
        int row  = mBase + r * 32 + s_sub;
        int srow = (MODE == MODE_QKV) ? src_row_idx(row) : row;
        arow[r] = srow;
        if constexpr (LN) {
            amean[r] = stats[srow * 2];
            arstd[r] = stats[srow * 2 + 1];
        }
    }

    f32x4 acc[4][4] = {};

    for (int t = 0; t < K / 64; ++t) {
        const int k0 = t * 64;
        if (t) __syncthreads();
        #pragma unroll
        for (int r = 0; r < 4; ++r)
            GL2LDS(bSrc + (size_t)r * 64 * K + (size_t)t * 128,
                   ldsB + r * 4096 + wid * 1024);
        float4 g0, g1v, b0, b1v;
        if constexpr (LN) {
            const int kk = k0 + chunk * 8;
            g0  = *(const float4*)&gamma[kk];
            g1v = *(const float4*)&gamma[kk + 4];
            b0  = *(const float4*)&beta[kk];
            b1v = *(const float4*)&beta[kk + 4];
        }
        #pragma unroll
        for (int r = 0; r < 4; ++r) {
            short8 av;
            if constexpr (LN) {
                const float* src = (const float*)Asrc_ + (size_t)arow[r] * K + k0 + chunk * 8;
                float4 v0 = *(const float4*)src;
                float4 v1 = *(const float4*)(src + 4);
                float m = amean[r], sd = arstd[r];
                bf16 tb[8];
                tb[0] = __float2bfloat16((v0.x - m) * sd * g0.x  + b0.x);
                tb[1] = __float2bfloat16((v0.y - m) * sd * g0.y  + b0.y);
                tb[2] = __float2bfloat16((v0.z - m) * sd * g0.z  + b0.z);
                tb[3] = __float2bfloat16((v0.w - m) * sd * g0.w  + b0.w);
                tb[4] = __float2bfloat16((v1.x - m) * sd * g1v.x + b1v.x);
                tb[5] = __float2bfloat16((v1.y - m) * sd * g1v.y + b1v.y);
                tb[6] = __float2bfloat16((v1.z - m) * sd * g1v.z + b1v.z);
                tb[7] = __float2bfloat16((v1.w - m) * sd * g1v.w + b1v.w);
                av = *(const short8*)tb;
            } else {
                av = *(const short8*)((const bf16*)Asrc_ + (size_t)arow[r] * K + k0 + chunk * 8);
            }
            *(short8*)(ldsA + (r * 32 + s_sub) * 128 + s_dst) = av;
        }
        __syncthreads();
        const int sw = (lrow & 7) << 4;
        #pragma unroll
        for (int ks = 0; ks < 2; ++ks) {
            const int kbl = (ks * 64 + lk * 16) ^ sw;
            short8 af[4], bfr[4];
            #pragma unroll
            for (int q = 0; q < 4; ++q) {
                af[q]  = *(const short8*)(ldsA + (wr * 64 + q * 16 + lrow) * 128 + kbl);
                bfr[q] = *(const short8*)(ldsB + (wc * 64 + q * 16 + lrow) * 128 + kbl);
            }
            #pragma unroll
            for (int mi = 0; mi < 4; ++mi)
                #pragma unroll
                for (int ni = 0; ni < 4; ++ni)
                    acc[mi][ni] = __builtin_amdgcn_mfma_f32_16x16x32_bf16(
                        af[mi], bfr[ni], acc[mi][ni], 0, 0, 0);
        }
    }

    // epilogue: ni innermost -> stores covering one line are consecutive
    const int cB = nBase + wc * 64 + lrow;
    const int rB = mBase + wr * 64 + lk * 4;
    float bs[4];
    #pragma unroll
    for (int ni = 0; ni < 4; ++ni) bs[ni] = bias[cB + ni * 16];
    #pragma unroll
    for (int mi = 0; mi < 4; ++mi) {
        #pragma unroll
        for (int i = 0; i < 4; ++i) {
            const int r = rB + mi * 16 + i;
            const int dst = (MODE == MODE_PROJ) ? src_row_idx(r) : r;
            #pragma unroll
            for (int ni = 0; ni < 4; ++ni) {
                const int c = cB + ni * 16;
                float v = acc[mi][ni][i] + bs[ni];
                if constexpr (MODE == MODE_QKV) {
                    float ve = __bfloat162float(vemb[(size_t)r * 256 + (c & 255)]);
                    v += (c >= 512) ? 2.f * ve : ve;
                    ((bf16*)outp)[(size_t)r * 768 + c] = __float2bfloat16(v);
                } else if constexpr (MODE == MODE_PROJ) {
                    ((float*)outp)[(size_t)dst * 256 + c] =
                        resid[(size_t)dst * 256 + c] + v;
                } else if constexpr (MODE == MODE_FC1) {
                    float gl = 0.5f * v * (1.f + erff(v * 0.70710678118f));
                    ((bf16*)outp)[(size_t)r * 1024 + c] = __float2bfloat16(gl);
                } else {
                    ((float*)outp)[(size_t)r * 256 + c] =
                        resid[(size_t)r * 256 + c] + v;
                }
            }
        }
    }
}

// ---------------- per-window attention: MFMA + RPE dedup ----------------
__global__ __launch_bounds__(256)
void attn_kernel(const bf16* __restrict__ qkv, const float* __restrict__ polar,
                 const float* __restrict__ rw1, const float* __restrict__ rb1,
                 const float* __restrict__ rw2, const float* __restrict__ rb2,
                 const float* __restrict__ tau, const float* __restrict__ mask,
                 bf16* __restrict__ outp) {
    const int w  = blockIdx.x;
    const int wl = w & 255;
    const int t  = threadIdx.x;
    const int lane = t & 63, wid = t >> 6;
    const int l15 = lane & 15, q4 = lane >> 4;
    const size_t wbase = (size_t)w * NWIN;

    __shared__ float pwx[NWIN], pwy[NWIN];
    __shared__ float rqn[8][64], rkn[8][64];
    __shared__ float cw1s[32], cb1s[16], cw2s[8][16], rb2s[8], scts[8];
    __shared__ bf16  rpem[4][2401];
    __shared__ short P_lds[64][72];
    __shared__ short VT[32][72];

    for (int i = t; i < 32 * 72; i += 256) ((short*)VT)[i] = 0;

    for (int u = t; u < 98; u += 256) {
        int n = u >> 1, cix = u & 1;
        int srow = src_row_idx(w * NWIN + n);
        float v = polar[(size_t)srow * 2 + cix];
        if (cix) pwy[n] = v; else pwx[n] = v;
    }
    if (t < 128) cw2s[t >> 4][t & 15] = rw2[t];
    else if (t < 160) cw1s[t - 128] = rw1[t - 128];
    else if (t < 176) cb1s[t - 160] = rb1[t - 160];
    else if (t < 184) rb2s[t - 176] = rb2[t - 176];
    else if (t < 192) scts[t - 184] = SCALE / fmaxf(tau[t - 184], 0.01f);

    for (int idx = t; idx < 8 * NWIN; idx += 256) {
        int h = idx / NWIN, n = idx - h * NWIN;
        const bf16* qp = qkv + (wbase + n) * 768 + h * 32;
        float sq = 0, sk = 0;
        #pragma unroll
        for (int c = 0; c < 4; ++c) {
            short8 qv = *(const short8*)(qp + c * 8);
            short8 kv = *(const short8*)(qp + 256 + c * 8);
            #pragma unroll
            for (int j = 0; j < 8; ++j) {
                float qf = bf2f(qv[j]); sq += qf * qf;
                float kf = bf2f(kv[j]); sk += kf * kf;
            }
        }
        rqn[h][n] = rsqrtf(sq);
        rkn[h][n] = rsqrtf(sk);
    }

    for (int g = 0; g < 2; ++g) {
        __syncthreads();
        for (int e = t; e < NWIN * NWIN; e += 256) {
            int n = e / NWIN, m = e - n * NWIN;
            float dx = pwx[n] - pwx[m], dy = pwy[n] - pwy[m];
            float hid[16];
            #pragma unroll
            for (int o = 0; o < 16; ++o)
                hid[o] = fmaxf(fmaf(cw1s[2*o], dx, fmaf(cw1s[2*o+1], dy, cb1s[o])), 0.f);
            float mv = mask[(size_t)wl * NWIN * NWIN + e];
            #pragma unroll
            for (int hh = 0; hh < 4; ++hh) {
                int h = 4 * g + hh;
                float a = rb2s[h] + mv;
                #pragma unroll
                for (int o = 0; o < 16; ++o) a = fmaf(hid[o], cw2s[h][o], a);
                rpem[hh][e] = __float2bfloat16(a);
            }
        }

        for (int hh = 0; hh < 4; ++hh) {
            const int h = 4 * g + hh;
            __syncthreads();

            {
                int n = t >> 2, ck = t & 3;
                if (n < NWIN) {
                    short8 vv8 = *(const short8*)(qkv + (wbase + n) * 768 + 512 + h * 32 + ck * 8);
                    #pragma unroll
                    for (int j = 0; j < 8; ++j) VT[ck * 8 + j][n] = vv8[j];
                }
            }

            short8 aq = {0,0,0,0,0,0,0,0};
            {
                int n = wid * 16 + l15;
                if (n < NWIN)
                    aq = *(const short8*)(qkv + (wbase + n) * 768 + h * 32 + q4 * 8);
            }
            short8 bk[4];
            #pragma unroll
            for (int c = 0; c < 4; ++c) {
                int m = c * 16 + l15;
                short8 z = {0,0,0,0,0,0,0,0};
                bk[c] = (m < NWIN)
                    ? *(const short8*)(qkv + (wbase + m) * 768 + 256 + h * 32 + q4 * 8)
                    : z;
            }
            f32x4 s[4] = {};
            #pragma unroll
            for (int c = 0; c < 4; ++c)
                s[c] = __builtin_amdgcn_mfma_f32_16x16x32_bf16(aq, bk[c], s[c], 0, 0, 0);

            const float sct = scts[h];
            float vv[4][4];
            #pragma unroll
            for (int c = 0; c < 4; ++c) {
                int m = c * 16 + l15;
                #pragma unroll
                for (int i = 0; i < 4; ++i) {
                    int n = wid * 16 + q4 * 4 + i;
                    float val = -1e30f;
                    if (n < NWIN && m < NWIN) {
                        float rr = fminf(rqn[h][n] * rkn[h][m], 1e6f);
                        val = s[c][i] * sct * rr + bf2f(*(short*)&rpem[hh][n * NWIN + m]);
                    }
                    vv[c][i] = val;
                }
            }

            #pragma unroll
            for (int i = 0; i < 4; ++i) {
                float mx = fmaxf(fmaxf(vv[0][i], vv[1][i]), fmaxf(vv[2][i], vv[3][i]));
                #pragma unroll
                for (int d = 1; d < 16; d <<= 1) mx = fmaxf(mx, __shfl_xor(mx, d));
                float sum = 0;
                #pragma unroll
                for (int c = 0; c < 4; ++c) {
                    float ev = __expf(vv[c][i] - mx);
                    vv[c][i] = ev; sum += ev;
                }
                #pragma unroll
                for (int d = 1; d < 16; d <<= 1) sum += __shfl_xor(sum, d);
                float inv = 1.0f / sum;
                #pragma unroll
                for (int c = 0; c < 4; ++c) vv[c][i] *= inv;
            }

            #pragma unroll
            for (int c = 0; c < 4; ++c)
                #pragma unroll
                for (int i = 0; i < 4; ++i) {
                    bf16 pb = __float2bfloat16(vv[c][i]);
                    short ps; __builtin_memcpy(&ps, &pb, 2);
                    P_lds[wid * 16 + q4 * 4 + i][c * 16 + l15] = ps;
                }

            __syncthreads();

            short8 pa[2];
            #pragma unroll
            for (int ks = 0; ks < 2; ++ks)
                pa[ks] = *(const short8*)&P_lds[wid * 16 + l15][ks * 32 + q4 * 8];
            f32x4 o[2] = {};
            #pragma unroll
            for (int ct = 0; ct < 2; ++ct) {
                #pragma unroll
                for (int ks = 0; ks < 2; ++ks) {
                    short8 vb = *(const short8*)&VT[ct * 16 + l15][ks * 32 + q4 * 8];
                    o[ct] = __builtin_amdgcn_mfma_f32_16x16x32_bf16(pa[ks], vb, o[ct], 0, 0, 0);
                }
            }
            #pragma unroll
            for (int ct = 0; ct < 2; ++ct)
                #pragma unroll
                for (int i = 0; i < 4; ++i) {
                    int n = wid * 16 + q4 * 4 + i;
                    if (n < NWIN)
                        outp[(wbase + n) * 256 + h * 32 + ct * 16 + l15] =
                            __float2bfloat16(o[ct][i]);
                }
        }
    }
}

// ---------------- launch ----------------
extern "C" void kernel_launch(void* const* d_in, const int* in_sizes, int n_in,
                              void* d_out, int out_size, void* d_ws, size_t ws_size,
                              hipStream_t stream) {
    const float* x     = (const float*)d_in[0];
    const float* mask  = (const float*)d_in[1];
    const float* polar = (const float*)d_in[2];
    const float* vote  = (const float*)d_in[3];
    const float* g1    = (const float*)d_in[4];
    const float* be1   = (const float*)d_in[5];
    const float* wqkv  = (const float*)d_in[6];
    const float* bqkv  = (const float*)d_in[7];
    const float* wproj = (const float*)d_in[8];
    const float* bproj = (const float*)d_in[9];
    const float* tau   = (const float*)d_in[10];
    const float* rw1   = (const float*)d_in[11];
    const float* rb1   = (const float*)d_in[12];
    const float* rw2   = (const float*)d_in[13];
    const float* rb2   = (const float*)d_in[14];
    const float* vw1   = (const float*)d_in[15];
    const float* vb1   = (const float*)d_in[16];
    const float* vw2   = (const float*)d_in[17];
    const float* vb2   = (const float*)d_in[18];
    const float* g2    = (const float*)d_in[19];
    const float* be2   = (const float*)d_in[20];
    const float* fc1w  = (const float*)d_in[21];
    const float* fc1b  = (const float*)d_in[22];
    const float* fc2w  = (const float*)d_in[23];
    const float* fc2b  = (const float*)d_in[24];
    float* out = (float*)d_out;

    // workspace (bytes), total ~105.1 MB (same plan as R4/R6)
    char* base = (char*)d_ws;
    bf16*  qkv     = (bf16*)base;
    bf16*  vemb    = (bf16*)(base + 77070336);
    bf16*  attnout = (bf16*)(base + 77070336);
    bf16*  hbuf    = (bf16*)base;
    bf16*  wqkvb   = (bf16*)(base + 102760448);
    bf16*  wprojb  = wqkvb + 768 * 256;
    bf16*  fc1wb   = wprojb + 256 * 256;
    bf16*  fc2wb   = fc1wb + 1024 * 256;
    float* stats1  = (float*)(base + 104333312);
    float* stats2  = stats1 + 2 * M;

    cvt_w<<<192, 256, 0, stream>>>(wqkv, wqkvb, 768*256/4);
    cvt_w<<<64,  256, 0, stream>>>(wproj, wprojb, 256*256/4);
    cvt_w<<<256, 256, 0, stream>>>(fc1w, fc1wb, 1024*256/4);
    cvt_w<<<256, 256, 0, stream>>>(fc2w, fc2wb, 256*1024/4);

    stats_kernel<<<M / 4, 256, 0, stream>>>(x, stats1);
    vemb_kernel<<<M / 4, 256, 0, stream>>>(vote, vw1, vb1, vw2, vb2, vemb);

    mfma_gemm<MODE_QKV, 6><<<(M / 128) * 6, 256, 0, stream>>>(
        x, wqkvb, bqkv, stats1, g1, be1, vemb, nullptr, qkv);

    attn_kernel<<<BT, 256, 0, stream>>>(qkv, polar, rw1, rb1, rw2, rb2, tau, mask, attnout);

    mfma_gemm<MODE_PROJ, 2><<<(M / 128) * 2, 256, 0, stream>>>(
        attnout, wprojb, bproj, nullptr, nullptr, nullptr, nullptr, x, out);

    stats_kernel<<<M / 4, 256, 0, stream>>>(out, stats2);

    mfma_gemm<MODE_FC1, 8><<<(M / 128) * 8, 256, 0, stream>>>(
        out, fc1wb, fc1b, stats2, g2, be2, nullptr, nullptr, hbuf);

    mfma_gemm<MODE_FC2, 2><<<(M / 128) * 2, 256, 0, stream>>>(
        hbuf, fc2wb, fc2b, nullptr, nullptr, nullptr, nullptr, out, out);
}

// Round 9
// 458.861 us; speedup vs baseline: 1.0851x; 1.0518x over previous
//
#include <hip/hip_runtime.h>
#include <hip/hip_bf16.h>
#include <math.h>

using bf16 = __hip_bfloat16;
typedef __attribute__((ext_vector_type(8))) short short8;
typedef __attribute__((ext_vector_type(4))) float f32x4;
typedef unsigned int u32;

// ---------------- problem constants ----------------
constexpr int BB    = 4;
constexpr int Hh    = 112;
constexpr int Ww    = 112;
constexpr int C     = 256;
constexpr int L     = Hh * Ww;        // 12544
constexpr int HEADS = 8;
constexpr int WS    = 7;
constexpr int SHIFT = 3;
constexpr int HID   = 1024;
constexpr int HD    = 32;
constexpr int NWIN  = 49;
constexpr int NW    = 256;
constexpr int BT    = BB * NW;        // 1024 windows
constexpr int M     = BT * NWIN;      // 50176 tokens
constexpr float SCALE = 0.17677669529663687f;
constexpr float EPS   = 1e-5f;

// window-token r -> natural token index. Same map for gather and scatter.
__device__ __forceinline__ int src_row_idx(int r) {
    int b_ = r / NWIN;
    int n  = r - b_ * NWIN;
    int b  = b_ >> 8;
    int w  = b_ & 255;
    int wh = w >> 4, ww = w & 15;
    int i  = n / WS, j = n - i * WS;
    int hp = wh * WS + i, wp = ww * WS + j;
    int h  = hp + SHIFT; if (h >= Hh) h -= Hh;
    int wc = wp + SHIFT; if (wc >= Ww) wc -= Ww;
    return b * L + h * Ww + wc;
}

__device__ __forceinline__ float bf2f(short s) {
    u32 u = ((u32)(unsigned short)s) << 16;
    float f; __builtin_memcpy(&f, &u, 4); return f;
}

#define GL2LDS(g, l) __builtin_amdgcn_global_load_lds( \
    (const __attribute__((address_space(1))) u32*)(const void*)(g), \
    (__attribute__((address_space(3))) u32*)(void*)(l), 16, 0, 0)

// ---------------- per-token LN stats (mean, rstd) ----------------
__global__ __launch_bounds__(256)
void stats_kernel(const float* __restrict__ x, float* __restrict__ stats) {
    int wave = threadIdx.x >> 6, lane = threadIdx.x & 63;
    int tok  = blockIdx.x * 4 + wave;
    const float4 v = *(const float4*)&x[(size_t)tok * C + lane * 4];
    float s  = v.x + v.y + v.z + v.w;
    float s2 = v.x*v.x + v.y*v.y + v.z*v.z + v.w*v.w;
    #pragma unroll
    for (int o = 32; o > 0; o >>= 1) {
        s  += __shfl_down(s, o);
        s2 += __shfl_down(s2, o);
    }
    if (lane == 0) {
        float m   = s * (1.0f / C);
        float var = s2 * (1.0f / C) - m * m;
        stats[tok * 2]     = m;
        stats[tok * 2 + 1] = rsqrtf(var + EPS);
    }
}

// ---------------- f32 -> bf16 weight convert ----------------
__global__ __launch_bounds__(256)
void cvt_w(const float* __restrict__ in, bf16* __restrict__ o, int n4) {
    int i = blockIdx.x * 256 + threadIdx.x;
    if (i >= n4) return;
    float4 v = *(const float4*)&in[(size_t)i * 4];
    bf16 t4[4] = {__float2bfloat16(v.x), __float2bfloat16(v.y),
                  __float2bfloat16(v.z), __float2bfloat16(v.w)};
    *(uint2*)&o[(size_t)i * 4] = *(const uint2*)t4;
}

// ---------------- vote-embed MLP: w2 in LDS, 1 thread per token ----------
__global__ __launch_bounds__(256)
void vemb_kernel(const float* __restrict__ vote,
                 const float* __restrict__ w1, const float* __restrict__ b1,
                 const float* __restrict__ w2, const float* __restrict__ b2,
                 bf16* __restrict__ vemb) {
    __shared__ float w2s[256][16];   // 16 KB; reads are wave-uniform -> broadcast
    __shared__ float b2s[256];
    __shared__ float w1s[48], b1s[16];
    const int tid = threadIdx.x;
    {   // stage weights once per block
        const float4* src = (const float4*)(w2 + tid * 16);
        float4* dst = (float4*)&w2s[tid][0];
        dst[0] = src[0]; dst[1] = src[1]; dst[2] = src[2]; dst[3] = src[3];
        b2s[tid] = b2[tid];
        if (tid < 48) w1s[tid] = w1[tid];
        else if (tid < 64) b1s[tid - 48] = b1[tid - 48];
    }
    __syncthreads();

    const int r = blockIdx.x * 256 + tid;
    const int srow = src_row_idx(r);
    const float v0 = vote[(size_t)srow * 3];
    const float v1 = vote[(size_t)srow * 3 + 1];
    const float v2 = vote[(size_t)srow * 3 + 2];
    float hid[16];
    #pragma unroll
    for (int o = 0; o < 16; ++o)
        hid[o] = fmaxf(fmaf(w1s[o*3], v0, fmaf(w1s[o*3+1], v1, fmaf(w1s[o*3+2], v2, b1s[o]))), 0.f);

    bf16* orow = vemb + (size_t)r * 256;
    for (int c0 = 0; c0 < 256; c0 += 8) {
        bf16 t8[8];
        #pragma unroll
        for (int j = 0; j < 8; ++j) {
            const int c = c0 + j;
            float a = b2s[c];
            #pragma unroll
            for (int o = 0; o < 16; ++o) a = fmaf(hid[o], w2s[c][o], a);
            t8[j] = __float2bfloat16(a);
        }
        *(uint4*)&orow[c0] = *(const uint4*)t8;
    }
}

// ---------------- MFMA GEMM (R8 structure) ----------
enum { MODE_QKV = 0, MODE_PROJ = 1, MODE_FC1 = 2, MODE_FC2 = 3 };

template <int MODE, int NT>
__global__ __launch_bounds__(256)
void mfma_gemm(const void* __restrict__ Asrc_, const bf16* __restrict__ Wb,
               const float* __restrict__ bias, const float* __restrict__ stats,
               const float* __restrict__ gamma, const float* __restrict__ beta,
               const bf16* __restrict__ vemb, const float* __restrict__ resid,
               void* __restrict__ outp) {
    constexpr int  K  = (MODE == MODE_FC2) ? 1024 : 256;
    constexpr bool LN = (MODE == MODE_QKV) || (MODE == MODE_FC1);
    __shared__ __align__(16) char lds[32768];
    char* ldsA = lds;
    char* ldsB = lds + 16384;

    const int tid  = threadIdx.x;
    const int lane = tid & 63;
    const int wid  = tid >> 6;
    const int wr   = wid >> 1, wc = wid & 1;
    const int lrow = lane & 15, lk = lane >> 4;
    const int bx = blockIdx.x / NT, by = blockIdx.x % NT;
    const int mBase = bx * 128, nBase = by * 128;

    const int s_sub = tid >> 3;
    const int chunk = tid & 7;
    const int s_dst = (chunk * 16) ^ ((s_sub & 7) << 4);
    const char* bSrc = (const char*)(Wb + (size_t)(nBase + s_sub) * K) + s_dst;

    int arow[4]; float amean[4], arstd[4];
    #pragma unroll
    for (int r = 0; r < 4; ++r) {
        int row  = mBase + r * 32 + s_sub;
        int srow = (MODE == MODE_QKV) ? src_row_idx(row) : row;
        arow[r] = srow;
        if constexpr (LN) {
            amean[r] = stats[srow * 2];
            arstd[r] = stats[srow * 2 + 1];
        }
    }

    f32x4 acc[4][4] = {};

    for (int t = 0; t < K / 64; ++t) {
        const int k0 = t * 64;
        if (t) __syncthreads();
        #pragma unroll
        for (int r = 0; r < 4; ++r)
            GL2LDS(bSrc + (size_t)r * 64 * K + (size_t)t * 128,
                   ldsB + r * 4096 + wid * 1024);
        float4 g0, g1v, b0, b1v;
        if constexpr (LN) {
            const int kk = k0 + chunk * 8;
            g0  = *(const float4*)&gamma[kk];
            g1v = *(const float4*)&gamma[kk + 4];
            b0  = *(const float4*)&beta[kk];
            b1v = *(const float4*)&beta[kk + 4];
        }
        #pragma unroll
        for (int r = 0; r < 4; ++r) {
            short8 av;
            if constexpr (LN) {
                const float* src = (const float*)Asrc_ + (size_t)arow[r] * K + k0 + chunk * 8;
                float4 v0 = *(const float4*)src;
                float4 v1 = *(const float4*)(src + 4);
                float m = amean[r], sd = arstd[r];
                bf16 tb[8];
                tb[0] = __float2bfloat16((v0.x - m) * sd * g0.x  + b0.x);
                tb[1] = __float2bfloat16((v0.y - m) * sd * g0.y  + b0.y);
                tb[2] = __float2bfloat16((v0.z - m) * sd * g0.z  + b0.z);
                tb[3] = __float2bfloat16((v0.w - m) * sd * g0.w  + b0.w);
                tb[4] = __float2bfloat16((v1.x - m) * sd * g1v.x + b1v.x);
                tb[5] = __float2bfloat16((v1.y - m) * sd * g1v.y + b1v.y);
                tb[6] = __float2bfloat16((v1.z - m) * sd * g1v.z + b1v.z);
                tb[7] = __float2bfloat16((v1.w - m) * sd * g1v.w + b1v.w);
                av = *(const short8*)tb;
            } else {
                av = *(const short8*)((const bf16*)Asrc_ + (size_t)arow[r] * K + k0 + chunk * 8);
            }
            *(short8*)(ldsA + (r * 32 + s_sub) * 128 + s_dst) = av;
        }
        __syncthreads();
        const int sw = (lrow & 7) << 4;
        #pragma unroll
        for (int ks = 0; ks < 2; ++ks) {
            const int kbl = (ks * 64 + lk * 16) ^ sw;
            short8 af[4], bfr[4];
            #pragma unroll
            for (int q = 0; q < 4; ++q) {
                af[q]  = *(const short8*)(ldsA + (wr * 64 + q * 16 + lrow) * 128 + kbl);
                bfr[q] = *(const short8*)(ldsB + (wc * 64 + q * 16 + lrow) * 128 + kbl);
            }
            #pragma unroll
            for (int mi = 0; mi < 4; ++mi)
                #pragma unroll
                for (int ni = 0; ni < 4; ++ni)
                    acc[mi][ni] = __builtin_amdgcn_mfma_f32_16x16x32_bf16(
                        af[mi], bfr[ni], acc[mi][ni], 0, 0, 0);
        }
    }

    const int cB = nBase + wc * 64 + lrow;
    const int rB = mBase + wr * 64 + lk * 4;
    float bs[4];
    #pragma unroll
    for (int ni = 0; ni < 4; ++ni) bs[ni] = bias[cB + ni * 16];
    #pragma unroll
    for (int mi = 0; mi < 4; ++mi) {
        #pragma unroll
        for (int i = 0; i < 4; ++i) {
            const int r = rB + mi * 16 + i;
            const int dst = (MODE == MODE_PROJ) ? src_row_idx(r) : r;
            #pragma unroll
            for (int ni = 0; ni < 4; ++ni) {
                const int c = cB + ni * 16;
                float v = acc[mi][ni][i] + bs[ni];
                if constexpr (MODE == MODE_QKV) {
                    float ve = __bfloat162float(vemb[(size_t)r * 256 + (c & 255)]);
                    v += (c >= 512) ? 2.f * ve : ve;
                    ((bf16*)outp)[(size_t)r * 768 + c] = __float2bfloat16(v);
                } else if constexpr (MODE == MODE_PROJ) {
                    ((float*)outp)[(size_t)dst * 256 + c] =
                        resid[(size_t)dst * 256 + c] + v;
                } else if constexpr (MODE == MODE_FC1) {
                    float gl = 0.5f * v * (1.f + erff(v * 0.70710678118f));
                    ((bf16*)outp)[(size_t)r * 1024 + c] = __float2bfloat16(gl);
                } else {
                    ((float*)outp)[(size_t)r * 256 + c] =
                        resid[(size_t)r * 256 + c] + v;
                }
            }
        }
    }
}

// ---------------- per-window attention: MFMA + RPE dedup ----------------
__global__ __launch_bounds__(256)
void attn_kernel(const bf16* __restrict__ qkv, const float* __restrict__ polar,
                 const float* __restrict__ rw1, const float* __restrict__ rb1,
                 const float* __restrict__ rw2, const float* __restrict__ rb2,
                 const float* __restrict__ tau, const float* __restrict__ mask,
                 bf16* __restrict__ outp) {
    const int w  = blockIdx.x;
    const int wl = w & 255;
    const int t  = threadIdx.x;
    const int lane = t & 63, wid = t >> 6;
    const int l15 = lane & 15, q4 = lane >> 4;
    const size_t wbase = (size_t)w * NWIN;

    __shared__ float pwx[NWIN], pwy[NWIN];
    __shared__ float rqn[8][64], rkn[8][64];
    __shared__ float cw1s[32], cb1s[16], cw2s[8][16], rb2s[8], scts[8];
    __shared__ bf16  rpem[4][2401];
    __shared__ short P_lds[64][72];
    __shared__ short VT[32][72];

    for (int i = t; i < 32 * 72; i += 256) ((short*)VT)[i] = 0;

    for (int u = t; u < 98; u += 256) {
        int n = u >> 1, cix = u & 1;
        int srow = src_row_idx(w * NWIN + n);
        float v = polar[(size_t)srow * 2 + cix];
        if (cix) pwy[n] = v; else pwx[n] = v;
    }
    if (t < 128) cw2s[t >> 4][t & 15] = rw2[t];
    else if (t < 160) cw1s[t - 128] = rw1[t - 128];
    else if (t < 176) cb1s[t - 160] = rb1[t - 160];
    else if (t < 184) rb2s[t - 176] = rb2[t - 176];
    else if (t < 192) scts[t - 184] = SCALE / fmaxf(tau[t - 184], 0.01f);

    for (int idx = t; idx < 8 * NWIN; idx += 256) {
        int h = idx / NWIN, n = idx - h * NWIN;
        const bf16* qp = qkv + (wbase + n) * 768 + h * 32;
        float sq = 0, sk = 0;
        #pragma unroll
        for (int c = 0; c < 4; ++c) {
            short8 qv = *(const short8*)(qp + c * 8);
            short8 kv = *(const short8*)(qp + 256 + c * 8);
            #pragma unroll
            for (int j = 0; j < 8; ++j) {
                float qf = bf2f(qv[j]); sq += qf * qf;
                float kf = bf2f(kv[j]); sk += kf * kf;
            }
        }
        rqn[h][n] = rsqrtf(sq);
        rkn[h][n] = rsqrtf(sk);
    }

    for (int g = 0; g < 2; ++g) {
        __syncthreads();
        for (int e = t; e < NWIN * NWIN; e += 256) {
            int n = e / NWIN, m = e - n * NWIN;
            float dx = pwx[n] - pwx[m], dy = pwy[n] - pwy[m];
            float hid[16];
            #pragma unroll
            for (int o = 0; o < 16; ++o)
                hid[o] = fmaxf(fmaf(cw1s[2*o], dx, fmaf(cw1s[2*o+1], dy, cb1s[o])), 0.f);
            float mv = mask[(size_t)wl * NWIN * NWIN + e];
            #pragma unroll
            for (int hh = 0; hh < 4; ++hh) {
                int h = 4 * g + hh;
                float a = rb2s[h] + mv;
                #pragma unroll
                for (int o = 0; o < 16; ++o) a = fmaf(hid[o], cw2s[h][o], a);
                rpem[hh][e] = __float2bfloat16(a);
            }
        }

        for (int hh = 0; hh < 4; ++hh) {
            const int h = 4 * g + hh;
            __syncthreads();

            {
                int n = t >> 2, ck = t & 3;
                if (n < NWIN) {
                    short8 vv8 = *(const short8*)(qkv + (wbase + n) * 768 + 512 + h * 32 + ck * 8);
                    #pragma unroll
                    for (int j = 0; j < 8; ++j) VT[ck * 8 + j][n] = vv8[j];
                }
            }

            short8 aq = {0,0,0,0,0,0,0,0};
            {
                int n = wid * 16 + l15;
                if (n < NWIN)
                    aq = *(const short8*)(qkv + (wbase + n) * 768 + h * 32 + q4 * 8);
            }
            short8 bk[4];
            #pragma unroll
            for (int c = 0; c < 4; ++c) {
                int m = c * 16 + l15;
                short8 z = {0,0,0,0,0,0,0,0};
                bk[c] = (m < NWIN)
                    ? *(const short8*)(qkv + (wbase + m) * 768 + 256 + h * 32 + q4 * 8)
                    : z;
            }
            f32x4 s[4] = {};
            #pragma unroll
            for (int c = 0; c < 4; ++c)
                s[c] = __builtin_amdgcn_mfma_f32_16x16x32_bf16(aq, bk[c], s[c], 0, 0, 0);

            const float sct = scts[h];
            float vv[4][4];
            #pragma unroll
            for (int c = 0; c < 4; ++c) {
                int m = c * 16 + l15;
                #pragma unroll
                for (int i = 0; i < 4; ++i) {
                    int n = wid * 16 + q4 * 4 + i;
                    float val = -1e30f;
                    if (n < NWIN && m < NWIN) {
                        float rr = fminf(rqn[h][n] * rkn[h][m], 1e6f);
                        val = s[c][i] * sct * rr + bf2f(*(short*)&rpem[hh][n * NWIN + m]);
                    }
                    vv[c][i] = val;
                }
            }

            #pragma unroll
            for (int i = 0; i < 4; ++i) {
                float mx = fmaxf(fmaxf(vv[0][i], vv[1][i]), fmaxf(vv[2][i], vv[3][i]));
                #pragma unroll
                for (int d = 1; d < 16; d <<= 1) mx = fmaxf(mx, __shfl_xor(mx, d));
                float sum = 0;
                #pragma unroll
                for (int c = 0; c < 4; ++c) {
                    float ev = __expf(vv[c][i] - mx);
                    vv[c][i] = ev; sum += ev;
                }
                #pragma unroll
                for (int d = 1; d < 16; d <<= 1) sum += __shfl_xor(sum, d);
                float inv = 1.0f / sum;
                #pragma unroll
                for (int c = 0; c < 4; ++c) vv[c][i] *= inv;
            }

            #pragma unroll
            for (int c = 0; c < 4; ++c)
                #pragma unroll
                for (int i = 0; i < 4; ++i) {
                    bf16 pb = __float2bfloat16(vv[c][i]);
                    short ps; __builtin_memcpy(&ps, &pb, 2);
                    P_lds[wid * 16 + q4 * 4 + i][c * 16 + l15] = ps;
                }

            __syncthreads();

            short8 pa[2];
            #pragma unroll
            for (int ks = 0; ks < 2; ++ks)
                pa[ks] = *(const short8*)&P_lds[wid * 16 + l15][ks * 32 + q4 * 8];
            f32x4 o[2] = {};
            #pragma unroll
            for (int ct = 0; ct < 2; ++ct) {
                #pragma unroll
                for (int ks = 0; ks < 2; ++ks) {
                    short8 vb = *(const short8*)&VT[ct * 16 + l15][ks * 32 + q4 * 8];
                    o[ct] = __builtin_amdgcn_mfma_f32_16x16x32_bf16(pa[ks], vb, o[ct], 0, 0, 0);
                }
            }
            #pragma unroll
            for (int ct = 0; ct < 2; ++ct)
                #pragma unroll
                for (int i = 0; i < 4; ++i) {
                    int n = wid * 16 + q4 * 4 + i;
                    if (n < NWIN)
                        outp[(wbase + n) * 256 + h * 32 + ct * 16 + l15] =
                            __float2bfloat16(o[ct][i]);
                }
        }
    }
}

// ---------------- launch ----------------
extern "C" void kernel_launch(void* const* d_in, const int* in_sizes, int n_in,
                              void* d_out, int out_size, void* d_ws, size_t ws_size,
                              hipStream_t stream) {
    const float* x     = (const float*)d_in[0];
    const float* mask  = (const float*)d_in[1];
    const float* polar = (const float*)d_in[2];
    const float* vote  = (const float*)d_in[3];
    const float* g1    = (const float*)d_in[4];
    const float* be1   = (const float*)d_in[5];
    const float* wqkv  = (const float*)d_in[6];
    const float* bqkv  = (const float*)d_in[7];
    const float* wproj = (const float*)d_in[8];
    const float* bproj = (const float*)d_in[9];
    const float* tau   = (const float*)d_in[10];
    const float* rw1   = (const float*)d_in[11];
    const float* rb1   = (const float*)d_in[12];
    const float* rw2   = (const float*)d_in[13];
    const float* rb2   = (const float*)d_in[14];
    const float* vw1   = (const float*)d_in[15];
    const float* vb1   = (const float*)d_in[16];
    const float* vw2   = (const float*)d_in[17];
    const float* vb2   = (const float*)d_in[18];
    const float* g2    = (const float*)d_in[19];
    const float* be2   = (const float*)d_in[20];
    const float* fc1w  = (const float*)d_in[21];
    const float* fc1b  = (const float*)d_in[22];
    const float* fc2w  = (const float*)d_in[23];
    const float* fc2b  = (const float*)d_in[24];
    float* out = (float*)d_out;

    // workspace (bytes), total ~105.1 MB (same plan as R4/R6)
    char* base = (char*)d_ws;
    bf16*  qkv     = (bf16*)base;
    bf16*  vemb    = (bf16*)(base + 77070336);
    bf16*  attnout = (bf16*)(base + 77070336);
    bf16*  hbuf    = (bf16*)base;
    bf16*  wqkvb   = (bf16*)(base + 102760448);
    bf16*  wprojb  = wqkvb + 768 * 256;
    bf16*  fc1wb   = wprojb + 256 * 256;
    bf16*  fc2wb   = fc1wb + 1024 * 256;
    float* stats1  = (float*)(base + 104333312);
    float* stats2  = stats1 + 2 * M;

    cvt_w<<<192, 256, 0, stream>>>(wqkv, wqkvb, 768*256/4);
    cvt_w<<<64,  256, 0, stream>>>(wproj, wprojb, 256*256/4);
    cvt_w<<<256, 256, 0, stream>>>(fc1w, fc1wb, 1024*256/4);
    cvt_w<<<256, 256, 0, stream>>>(fc2w, fc2wb, 256*1024/4);

    stats_kernel<<<M / 4, 256, 0, stream>>>(x, stats1);
    vemb_kernel<<<M / 256, 256, 0, stream>>>(vote, vw1, vb1, vw2, vb2, vemb);

    mfma_gemm<MODE_QKV, 6><<<(M / 128) * 6, 256, 0, stream>>>(
        x, wqkvb, bqkv, stats1, g1, be1, vemb, nullptr, qkv);

    attn_kernel<<<BT, 256, 0, stream>>>(qkv, polar, rw1, rb1, rw2, rb2, tau, mask, attnout);

    mfma_gemm<MODE_PROJ, 2><<<(M / 128) * 2, 256, 0, stream>>>(
        attnout, wprojb, bproj, nullptr, nullptr, nullptr, nullptr, x, out);

    stats_kernel<<<M / 4, 256, 0, stream>>>(out, stats2);

    mfma_gemm<MODE_FC1, 8><<<(M / 128) * 8, 256, 0, stream>>>(
        out, fc1wb, fc1b, stats2, g2, be2, nullptr, nullptr, hbuf);

    mfma_gemm<MODE_FC2, 2><<<(M / 128) * 2, 256, 0, stream>>>(
        hbuf, fc2wb, fc2b, nullptr, nullptr, nullptr, nullptr, out, out);
}

// Round 10
// 428.664 us; speedup vs baseline: 1.1615x; 1.0704x over previous
//
#include <hip/hip_runtime.h>
#include <hip/hip_bf16.h>
#include <math.h>

using bf16 = __hip_bfloat16;
typedef __attribute__((ext_vector_type(8))) short short8;
typedef __attribute__((ext_vector_type(4))) float f32x4;
typedef unsigned int u32;

// ---------------- problem constants ----------------
constexpr int BB    = 4;
constexpr int Hh    = 112;
constexpr int Ww    = 112;
constexpr int C     = 256;
constexpr int L     = Hh * Ww;        // 12544
constexpr int HEADS = 8;
constexpr int WS    = 7;
constexpr int SHIFT = 3;
constexpr int HID   = 1024;
constexpr int HD    = 32;
constexpr int NWIN  = 49;
constexpr int NW    = 256;
constexpr int BT    = BB * NW;        // 1024 windows
constexpr int M     = BT * NWIN;      // 50176 tokens
constexpr float SCALE = 0.17677669529663687f;
constexpr float EPS   = 1e-5f;

// window-token r -> natural token index. Same map for gather and scatter.
__device__ __forceinline__ int src_row_idx(int r) {
    int b_ = r / NWIN;
    int n  = r - b_ * NWIN;
    int b  = b_ >> 8;
    int w  = b_ & 255;
    int wh = w >> 4, ww = w & 15;
    int i  = n / WS, j = n - i * WS;
    int hp = wh * WS + i, wp = ww * WS + j;
    int h  = hp + SHIFT; if (h >= Hh) h -= Hh;
    int wc = wp + SHIFT; if (wc >= Ww) wc -= Ww;
    return b * L + h * Ww + wc;
}

__device__ __forceinline__ float bf2f(short s) {
    u32 u = ((u32)(unsigned short)s) << 16;
    float f; __builtin_memcpy(&f, &u, 4); return f;
}
__device__ __forceinline__ short f2bfbits(float f) {
    bf16 b = __float2bfloat16(f);
    short s; __builtin_memcpy(&s, &b, 2); return s;
}
__device__ __forceinline__ u32 pack2bf(float lo, float hi) {
    return (u32)(unsigned short)f2bfbits(lo) | ((u32)(unsigned short)f2bfbits(hi) << 16);
}

#define GL2LDS(g, l) __builtin_amdgcn_global_load_lds( \
    (const __attribute__((address_space(1))) u32*)(const void*)(g), \
    (__attribute__((address_space(3))) u32*)(void*)(l), 16, 0, 0)

// ---------------- per-token LN stats (mean, rstd) ----------------
__global__ __launch_bounds__(256)
void stats_kernel(const float* __restrict__ x, float* __restrict__ stats) {
    int wave = threadIdx.x >> 6, lane = threadIdx.x & 63;
    int tok  = blockIdx.x * 4 + wave;
    const float4 v = *(const float4*)&x[(size_t)tok * C + lane * 4];
    float s  = v.x + v.y + v.z + v.w;
    float s2 = v.x*v.x + v.y*v.y + v.z*v.z + v.w*v.w;
    #pragma unroll
    for (int o = 32; o > 0; o >>= 1) {
        s  += __shfl_down(s, o);
        s2 += __shfl_down(s2, o);
    }
    if (lane == 0) {
        float m   = s * (1.0f / C);
        float var = s2 * (1.0f / C) - m * m;
        stats[tok * 2]     = m;
        stats[tok * 2 + 1] = rsqrtf(var + EPS);
    }
}

// ---------------- f32 -> bf16 weight convert ----------------
__global__ __launch_bounds__(256)
void cvt_w(const float* __restrict__ in, bf16* __restrict__ o, int n4) {
    int i = blockIdx.x * 256 + threadIdx.x;
    if (i >= n4) return;
    float4 v = *(const float4*)&in[(size_t)i * 4];
    bf16 t4[4] = {__float2bfloat16(v.x), __float2bfloat16(v.y),
                  __float2bfloat16(v.z), __float2bfloat16(v.w)};
    *(uint2*)&o[(size_t)i * 4] = *(const uint2*)t4;
}

// ---------------- vote-embed MLP: w2 in LDS, 1 thread per token ----------
__global__ __launch_bounds__(256)
void vemb_kernel(const float* __restrict__ vote,
                 const float* __restrict__ w1, const float* __restrict__ b1,
                 const float* __restrict__ w2, const float* __restrict__ b2,
                 bf16* __restrict__ vemb) {
    __shared__ float w2s[256][16];
    __shared__ float b2s[256];
    __shared__ float w1s[48], b1s[16];
    const int tid = threadIdx.x;
    {
        const float4* src = (const float4*)(w2 + tid * 16);
        float4* dst = (float4*)&w2s[tid][0];
        dst[0] = src[0]; dst[1] = src[1]; dst[2] = src[2]; dst[3] = src[3];
        b2s[tid] = b2[tid];
        if (tid < 48) w1s[tid] = w1[tid];
        else if (tid < 64) b1s[tid - 48] = b1[tid - 48];
    }
    __syncthreads();

    const int r = blockIdx.x * 256 + tid;
    const int srow = src_row_idx(r);
    const float v0 = vote[(size_t)srow * 3];
    const float v1 = vote[(size_t)srow * 3 + 1];
    const float v2 = vote[(size_t)srow * 3 + 2];
    float hid[16];
    #pragma unroll
    for (int o = 0; o < 16; ++o)
        hid[o] = fmaxf(fmaf(w1s[o*3], v0, fmaf(w1s[o*3+1], v1, fmaf(w1s[o*3+2], v2, b1s[o]))), 0.f);

    bf16* orow = vemb + (size_t)r * 256;
    for (int c0 = 0; c0 < 256; c0 += 8) {
        bf16 t8[8];
        #pragma unroll
        for (int j = 0; j < 8; ++j) {
            const int c = c0 + j;
            float a = b2s[c];
            #pragma unroll
            for (int o = 0; o < 16; ++o) a = fmaf(hid[o], w2s[c][o], a);
            t8[j] = __float2bfloat16(a);
        }
        *(uint4*)&orow[c0] = *(const uint4*)t8;
    }
}

// ---------------- MFMA GEMM (R9 structure, unchanged) ----------
enum { MODE_QKV = 0, MODE_PROJ = 1, MODE_FC1 = 2, MODE_FC2 = 3 };

template <int MODE, int NT>
__global__ __launch_bounds__(256)
void mfma_gemm(const void* __restrict__ Asrc_, const bf16* __restrict__ Wb,
               const float* __restrict__ bias, const float* __restrict__ stats,
               const float* __restrict__ gamma, const float* __restrict__ beta,
               const bf16* __restrict__ vemb, const float* __restrict__ resid,
               void* __restrict__ outp) {
    constexpr int  K  = (MODE == MODE_FC2) ? 1024 : 256;
    constexpr bool LN = (MODE == MODE_QKV) || (MODE == MODE_FC1);
    __shared__ __align__(16) char lds[32768];
    char* ldsA = lds;
    char* ldsB = lds + 16384;

    const int tid  = threadIdx.x;
    const int lane = tid & 63;
    const int wid  = tid >> 6;
    const int wr   = wid >> 1, wc = wid & 1;
    const int lrow = lane & 15, lk = lane >> 4;
    const int bx = blockIdx.x / NT, by = blockIdx.x % NT;
    const int mBase = bx * 128, nBase = by * 128;

    const int s_sub = tid >> 3;
    const int chunk = tid & 7;
    const int s_dst = (chunk * 16) ^ ((s_sub & 7) << 4);
    const char* bSrc = (const char*)(Wb + (size_t)(nBase + s_sub) * K) + s_dst;

    int arow[4]; float amean[4], arstd[4];
    #pragma unroll
    for (int r = 0; r < 4; ++r) {
        int row  = mBase + r * 32 + s_sub;
        int srow = (MODE == MODE_QKV) ? src_row_idx(row) : row;
        arow[r] = srow;
        if constexpr (LN) {
            amean[r] = stats[srow * 2];
            arstd[r] = stats[srow * 2 + 1];
        }
    }

    f32x4 acc[4][4] = {};

    for (int t = 0; t < K / 64; ++t) {
        const int k0 = t * 64;
        if (t) __syncthreads();
        #pragma unroll
        for (int r = 0; r < 4; ++r)
            GL2LDS(bSrc + (size_t)r * 64 * K + (size_t)t * 128,
                   ldsB + r * 4096 + wid * 1024);
        float4 g0, g1v, b0, b1v;
        if constexpr (LN) {
            const int kk = k0 + chunk * 8;
            g0  = *(const float4*)&gamma[kk];
            g1v = *(const float4*)&gamma[kk + 4];
            b0  = *(const float4*)&beta[kk];
            b1v = *(const float4*)&beta[kk + 4];
        }
        #pragma unroll
        for (int r = 0; r < 4; ++r) {
            short8 av;
            if constexpr (LN) {
                const float* src = (const float*)Asrc_ + (size_t)arow[r] * K + k0 + chunk * 8;
                float4 v0 = *(const float4*)src;
                float4 v1 = *(const float4*)(src + 4);
                float m = amean[r], sd = arstd[r];
                bf16 tb[8];
                tb[0] = __float2bfloat16((v0.x - m) * sd * g0.x  + b0.x);
                tb[1] = __float2bfloat16((v0.y - m) * sd * g0.y  + b0.y);
                tb[2] = __float2bfloat16((v0.z - m) * sd * g0.z  + b0.z);
                tb[3] = __float2bfloat16((v0.w - m) * sd * g0.w  + b0.w);
                tb[4] = __float2bfloat16((v1.x - m) * sd * g1v.x + b1v.x);
                tb[5] = __float2bfloat16((v1.y - m) * sd * g1v.y + b1v.y);
                tb[6] = __float2bfloat16((v1.z - m) * sd * g1v.z + b1v.z);
                tb[7] = __float2bfloat16((v1.w - m) * sd * g1v.w + b1v.w);
                av = *(const short8*)tb;
            } else {
                av = *(const short8*)((const bf16*)Asrc_ + (size_t)arow[r] * K + k0 + chunk * 8);
            }
            *(short8*)(ldsA + (r * 32 + s_sub) * 128 + s_dst) = av;
        }
        __syncthreads();
        const int sw = (lrow & 7) << 4;
        #pragma unroll
        for (int ks = 0; ks < 2; ++ks) {
            const int kbl = (ks * 64 + lk * 16) ^ sw;
            short8 af[4], bfr[4];
            #pragma unroll
            for (int q = 0; q < 4; ++q) {
                af[q]  = *(const short8*)(ldsA + (wr * 64 + q * 16 + lrow) * 128 + kbl);
                bfr[q] = *(const short8*)(ldsB + (wc * 64 + q * 16 + lrow) * 128 + kbl);
            }
            #pragma unroll
            for (int mi = 0; mi < 4; ++mi)
                #pragma unroll
                for (int ni = 0; ni < 4; ++ni)
                    acc[mi][ni] = __builtin_amdgcn_mfma_f32_16x16x32_bf16(
                        af[mi], bfr[ni], acc[mi][ni], 0, 0, 0);
        }
    }

    const int cB = nBase + wc * 64 + lrow;
    const int rB = mBase + wr * 64 + lk * 4;
    float bs[4];
    #pragma unroll
    for (int ni = 0; ni < 4; ++ni) bs[ni] = bias[cB + ni * 16];
    #pragma unroll
    for (int mi = 0; mi < 4; ++mi) {
        #pragma unroll
        for (int i = 0; i < 4; ++i) {
            const int r = rB + mi * 16 + i;
            const int dst = (MODE == MODE_PROJ) ? src_row_idx(r) : r;
            #pragma unroll
            for (int ni = 0; ni < 4; ++ni) {
                const int c = cB + ni * 16;
                float v = acc[mi][ni][i] + bs[ni];
                if constexpr (MODE == MODE_QKV) {
                    float ve = __bfloat162float(vemb[(size_t)r * 256 + (c & 255)]);
                    v += (c >= 512) ? 2.f * ve : ve;
                    ((bf16*)outp)[(size_t)r * 768 + c] = __float2bfloat16(v);
                } else if constexpr (MODE == MODE_PROJ) {
                    ((float*)outp)[(size_t)dst * 256 + c] =
                        resid[(size_t)dst * 256 + c] + v;
                } else if constexpr (MODE == MODE_FC1) {
                    float gl = 0.5f * v * (1.f + erff(v * 0.70710678118f));
                    ((bf16*)outp)[(size_t)r * 1024 + c] = __float2bfloat16(gl);
                } else {
                    ((float*)outp)[(size_t)r * 256 + c] =
                        resid[(size_t)r * 256 + c] + v;
                }
            }
        }
    }
}

// ---------------- attention v3: head-parallel, zero inner barriers ---------
// Block = 1 window (256 thr, 4 waves). Wave w handles heads {w, w+4} fully
// independently after a single shared RPE phase (all 8 heads, computed once).
// Swapped QK^T: st[at][nt] = mfma(K_at, Q_nt) -> lane(q4,l15) reg i holds
// S[n=nt*16+l15][m=at*16+q4*4+i]. Softmax: in-lane 16 + shfl_xor(16,32).
// PV A-frags via 2-shfl+select word transfers (no LDS round trip).
__global__ __launch_bounds__(256)
void attn_kernel(const bf16* __restrict__ qkv, const float* __restrict__ polar,
                 const float* __restrict__ rw1, const float* __restrict__ rb1,
                 const float* __restrict__ rw2, const float* __restrict__ rb2,
                 const float* __restrict__ tau, const float* __restrict__ mask,
                 bf16* __restrict__ outp) {
    const int w  = blockIdx.x;
    const int wl = w & 255;
    const int t  = threadIdx.x;
    const int lane = t & 63, wid = t >> 6;
    const int l15 = lane & 15, q4 = lane >> 4;
    const size_t wbase = (size_t)w * NWIN;
    const short* qs = (const short*)qkv;

    __shared__ float pwx[NWIN], pwy[NWIN];
    __shared__ float rqn[8][64], rkn[8][64];
    __shared__ float cw1s[32], cb1s[16], cw2s[8][16], rb2s[8], scts[8];
    __shared__ short rpem[8][2401];     // bf16 bits of (rpe + rb2 + mask)

    // ---- phase A: constants, polar coords, q/k reciprocal norms ----
    if (t < 98) {
        int n = t >> 1, cix = t & 1;
        int srow = src_row_idx(w * NWIN + n);
        float v = polar[(size_t)srow * 2 + cix];
        if (cix) pwy[n] = v; else pwx[n] = v;
    }
    if (t >= 128 && t < 256) {
        int u = t - 128;
        if (u < 128) cw2s[u >> 4][u & 15] = rw2[u];
    }
    if (t < 32) cw1s[t] = rw1[t];
    else if (t < 48) cb1s[t - 32] = rb1[t - 32];
    else if (t < 56) rb2s[t - 48] = rb2[t - 48];
    else if (t < 64) scts[t - 56] = SCALE / fmaxf(tau[t - 56], 0.01f);

    for (int idx = t; idx < 8 * NWIN; idx += 256) {
        int h = idx / NWIN, n = idx - h * NWIN;
        const bf16* qp = qkv + (wbase + n) * 768 + h * 32;
        float sq = 0, sk = 0;
        #pragma unroll
        for (int c = 0; c < 4; ++c) {
            short8 qv = *(const short8*)(qp + c * 8);
            short8 kv = *(const short8*)(qp + 256 + c * 8);
            #pragma unroll
            for (int j = 0; j < 8; ++j) {
                float qf = bf2f(qv[j]); sq += qf * qf;
                float kf = bf2f(kv[j]); sk += kf * kf;
            }
        }
        rqn[h][n] = rsqrtf(sq);
        rkn[h][n] = rsqrtf(sk);
    }
    __syncthreads();

    // ---- phase B: RPE for ALL 8 heads, hidden MLP computed once ----
    for (int e = t; e < NWIN * NWIN; e += 256) {
        int n = e / NWIN, m = e - n * NWIN;
        float dx = pwx[n] - pwx[m], dy = pwy[n] - pwy[m];
        float hid[16];
        #pragma unroll
        for (int o = 0; o < 16; ++o)
            hid[o] = fmaxf(fmaf(cw1s[2*o], dx, fmaf(cw1s[2*o+1], dy, cb1s[o])), 0.f);
        float mv = mask[(size_t)wl * NWIN * NWIN + e];
        #pragma unroll
        for (int h = 0; h < 8; ++h) {
            float a = rb2s[h] + mv;
            #pragma unroll
            for (int o = 0; o < 16; ++o) a = fmaf(hid[o], cw2s[h][o], a);
            rpem[h][e] = f2bfbits(a);
        }
    }
    __syncthreads();

    // ---- phase C: per-wave, 2 heads, no barriers ----
    const short8 z8 = {0,0,0,0,0,0,0,0};
    const int qa  = (q4 & 1) * 2;
    const int sel = q4 >> 1;

    for (int hh = 0; hh < 2; ++hh) {
        const int h = wid + hh * 4;
        const bf16* hbase = qkv + wbase * 768 + h * 32;
        const float sct = scts[h];

        // K (A-frags) and Q (B-frags)
        short8 kf[4], qf[4];
        #pragma unroll
        for (int at = 0; at < 4; ++at) {
            int m = at * 16 + l15;
            kf[at] = (m < NWIN) ? *(const short8*)(hbase + (size_t)m * 768 + 256 + q4 * 8) : z8;
        }
        #pragma unroll
        for (int nt = 0; nt < 4; ++nt) {
            int n = nt * 16 + l15;
            qf[nt] = (n < NWIN) ? *(const short8*)(hbase + (size_t)n * 768 + q4 * 8) : z8;
        }
        // V B-frags: vb[ks][ct] elem j = V[m=ks*32+q4*8+j][d=ct*16+l15]
        short8 vb[2][2];
        #pragma unroll
        for (int ks = 0; ks < 2; ++ks)
            #pragma unroll
            for (int ct = 0; ct < 2; ++ct) {
                short tmp[8];
                #pragma unroll
                for (int j = 0; j < 8; ++j) {
                    int m = ks * 32 + q4 * 8 + j;
                    tmp[j] = (m < NWIN)
                        ? qs[(wbase + m) * 768 + 512 + h * 32 + ct * 16 + l15]
                        : (short)0;
                }
                __builtin_memcpy(&vb[ks][ct], tmp, 16);
            }

        // QK^T (swapped) + softmax per nt; pack P rows to bf16 words
        u32 pw[4][4][2];            // [nt][at][word]
        const f32x4 zf = {0.f, 0.f, 0.f, 0.f};
        #pragma unroll
        for (int nt = 0; nt < 4; ++nt) {
            f32x4 sacc[4];
            #pragma unroll
            for (int at = 0; at < 4; ++at)
                sacc[at] = __builtin_amdgcn_mfma_f32_16x16x32_bf16(kf[at], qf[nt], zf, 0, 0, 0);
            const int n = nt * 16 + l15;
            const float rq = rqn[h][n];
            float pv[4][4];
            #pragma unroll
            for (int at = 0; at < 4; ++at)
                #pragma unroll
                for (int i = 0; i < 4; ++i) {
                    int m = at * 16 + q4 * 4 + i;
                    float val = -1e30f;
                    if (n < NWIN && m < NWIN) {
                        float rr = fminf(rq * rkn[h][m], 1e6f);
                        val = sacc[at][i] * sct * rr + bf2f(rpem[h][n * NWIN + m]);
                    }
                    pv[at][i] = val;
                }
            float mx = -1e30f;
            #pragma unroll
            for (int at = 0; at < 4; ++at)
                #pragma unroll
                for (int i = 0; i < 4; ++i) mx = fmaxf(mx, pv[at][i]);
            mx = fmaxf(mx, __shfl_xor(mx, 16));
            mx = fmaxf(mx, __shfl_xor(mx, 32));
            float sum = 0.f;
            #pragma unroll
            for (int at = 0; at < 4; ++at)
                #pragma unroll
                for (int i = 0; i < 4; ++i) {
                    float ev = __expf(pv[at][i] - mx);
                    pv[at][i] = ev; sum += ev;
                }
            sum += __shfl_xor(sum, 16);
            sum += __shfl_xor(sum, 32);
            const float inv = 1.0f / sum;
            #pragma unroll
            for (int at = 0; at < 4; ++at) {
                pw[nt][at][0] = pack2bf(pv[at][0] * inv, pv[at][1] * inv);
                pw[nt][at][1] = pack2bf(pv[at][2] * inv, pv[at][3] * inv);
            }
        }

        // PV: redistribute P via shfl word transfers, then MFMA
        f32x4 o[4][2] = {};
        #pragma unroll
        for (int nt = 0; nt < 4; ++nt) {
            #pragma unroll
            for (int ks = 0; ks < 2; ++ks) {
                u32 wv[4];
                #pragma unroll
                for (int w_ = 0; w_ < 4; ++w_) {
                    int srcl = l15 + (qa + (w_ >> 1)) * 16;
                    u32 lo = (u32)__shfl((int)pw[nt][2 * ks][w_ & 1], srcl);
                    u32 hi = (u32)__shfl((int)pw[nt][2 * ks + 1][w_ & 1], srcl);
                    wv[w_] = sel ? hi : lo;
                }
                short8 pa;
                __builtin_memcpy(&pa, wv, 16);
                #pragma unroll
                for (int ct = 0; ct < 2; ++ct)
                    o[nt][ct] = __builtin_amdgcn_mfma_f32_16x16x32_bf16(pa, vb[ks][ct], o[nt][ct], 0, 0, 0);
            }
        }

        // write O[n][d]: lane reg i -> n = nt*16+q4*4+i, d = ct*16+l15
        #pragma unroll
        for (int nt = 0; nt < 4; ++nt)
            #pragma unroll
            for (int ct = 0; ct < 2; ++ct)
                #pragma unroll
                for (int i = 0; i < 4; ++i) {
                    int n = nt * 16 + q4 * 4 + i;
                    if (n < NWIN)
                        outp[(wbase + n) * 256 + h * 32 + ct * 16 + l15] =
                            __float2bfloat16(o[nt][ct][i]);
                }
    }
}

// ---------------- launch ----------------
extern "C" void kernel_launch(void* const* d_in, const int* in_sizes, int n_in,
                              void* d_out, int out_size, void* d_ws, size_t ws_size,
                              hipStream_t stream) {
    const float* x     = (const float*)d_in[0];
    const float* mask  = (const float*)d_in[1];
    const float* polar = (const float*)d_in[2];
    const float* vote  = (const float*)d_in[3];
    const float* g1    = (const float*)d_in[4];
    const float* be1   = (const float*)d_in[5];
    const float* wqkv  = (const float*)d_in[6];
    const float* bqkv  = (const float*)d_in[7];
    const float* wproj = (const float*)d_in[8];
    const float* bproj = (const float*)d_in[9];
    const float* tau   = (const float*)d_in[10];
    const float* rw1   = (const float*)d_in[11];
    const float* rb1   = (const float*)d_in[12];
    const float* rw2   = (const float*)d_in[13];
    const float* rb2   = (const float*)d_in[14];
    const float* vw1   = (const float*)d_in[15];
    const float* vb1   = (const float*)d_in[16];
    const float* vw2   = (const float*)d_in[17];
    const float* vb2   = (const float*)d_in[18];
    const float* g2    = (const float*)d_in[19];
    const float* be2   = (const float*)d_in[20];
    const float* fc1w  = (const float*)d_in[21];
    const float* fc1b  = (const float*)d_in[22];
    const float* fc2w  = (const float*)d_in[23];
    const float* fc2b  = (const float*)d_in[24];
    float* out = (float*)d_out;

    // workspace (bytes), total ~105.1 MB (same plan as R4/R6)
    char* base = (char*)d_ws;
    bf16*  qkv     = (bf16*)base;
    bf16*  vemb    = (bf16*)(base + 77070336);
    bf16*  attnout = (bf16*)(base + 77070336);
    bf16*  hbuf    = (bf16*)base;
    bf16*  wqkvb   = (bf16*)(base + 102760448);
    bf16*  wprojb  = wqkvb + 768 * 256;
    bf16*  fc1wb   = wprojb + 256 * 256;
    bf16*  fc2wb   = fc1wb + 1024 * 256;
    float* stats1  = (float*)(base + 104333312);
    float* stats2  = stats1 + 2 * M;

    cvt_w<<<192, 256, 0, stream>>>(wqkv, wqkvb, 768*256/4);
    cvt_w<<<64,  256, 0, stream>>>(wproj, wprojb, 256*256/4);
    cvt_w<<<256, 256, 0, stream>>>(fc1w, fc1wb, 1024*256/4);
    cvt_w<<<256, 256, 0, stream>>>(fc2w, fc2wb, 256*1024/4);

    stats_kernel<<<M / 4, 256, 0, stream>>>(x, stats1);
    vemb_kernel<<<M / 256, 256, 0, stream>>>(vote, vw1, vb1, vw2, vb2, vemb);

    mfma_gemm<MODE_QKV, 6><<<(M / 128) * 6, 256, 0, stream>>>(
        x, wqkvb, bqkv, stats1, g1, be1, vemb, nullptr, qkv);

    attn_kernel<<<BT, 256, 0, stream>>>(qkv, polar, rw1, rb1, rw2, rb2, tau, mask, attnout);

    mfma_gemm<MODE_PROJ, 2><<<(M / 128) * 2, 256, 0, stream>>>(
        attnout, wprojb, bproj, nullptr, nullptr, nullptr, nullptr, x, out);

    stats_kernel<<<M / 4, 256, 0, stream>>>(out, stats2);

    mfma_gemm<MODE_FC1, 8><<<(M / 128) * 8, 256, 0, stream>>>(
        out, fc1wb, fc1b, stats2, g2, be2, nullptr, nullptr, hbuf);

    mfma_gemm<MODE_FC2, 2><<<(M / 128) * 2, 256, 0, stream>>>(
        hbuf, fc2wb, fc2b, nullptr, nullptr, nullptr, nullptr, out, out);
}

// Round 11
// 369.196 us; speedup vs baseline: 1.3486x; 1.1611x over previous
//
#include <hip/hip_runtime.h>
#include <hip/hip_bf16.h>
#include <math.h>

using bf16 = __hip_bfloat16;
typedef __attribute__((ext_vector_type(8))) short short8;
typedef __attribute__((ext_vector_type(4))) float f32x4;
typedef unsigned int u32;

// ---------------- problem constants ----------------
constexpr int BB    = 4;
constexpr int Hh    = 112;
constexpr int Ww    = 112;
constexpr int C     = 256;
constexpr int L     = Hh * Ww;        // 12544
constexpr int HEADS = 8;
constexpr int WS    = 7;
constexpr int SHIFT = 3;
constexpr int HID   = 1024;
constexpr int HD    = 32;
constexpr int NWIN  = 49;
constexpr int NW    = 256;
constexpr int BT    = BB * NW;        // 1024 windows
constexpr int M     = BT * NWIN;      // 50176 tokens
constexpr float SCALE = 0.17677669529663687f;
constexpr float EPS   = 1e-5f;

// window-token r -> natural token index. Same map for gather and scatter.
__device__ __forceinline__ int src_row_idx(int r) {
    int b_ = r / NWIN;
    int n  = r - b_ * NWIN;
    int b  = b_ >> 8;
    int w  = b_ & 255;
    int wh = w >> 4, ww = w & 15;
    int i  = n / WS, j = n - i * WS;
    int hp = wh * WS + i, wp = ww * WS + j;
    int h  = hp + SHIFT; if (h >= Hh) h -= Hh;
    int wc = wp + SHIFT; if (wc >= Ww) wc -= Ww;
    return b * L + h * Ww + wc;
}

__device__ __forceinline__ float bf2f(short s) {
    u32 u = ((u32)(unsigned short)s) << 16;
    float f; __builtin_memcpy(&f, &u, 4); return f;
}
__device__ __forceinline__ short f2bfbits(float f) {
    bf16 b = __float2bfloat16(f);
    short s; __builtin_memcpy(&s, &b, 2); return s;
}
__device__ __forceinline__ u32 pack2bf(float lo, float hi) {
    return (u32)(unsigned short)f2bfbits(lo) | ((u32)(unsigned short)f2bfbits(hi) << 16);
}

#define GL2LDS(g, l) __builtin_amdgcn_global_load_lds( \
    (const __attribute__((address_space(1))) u32*)(const void*)(g), \
    (__attribute__((address_space(3))) u32*)(void*)(l), 16, 0, 0)

// ---------------- per-token LN stats (mean, rstd) ----------------
__global__ __launch_bounds__(256)
void stats_kernel(const float* __restrict__ x, float* __restrict__ stats) {
    int wave = threadIdx.x >> 6, lane = threadIdx.x & 63;
    int tok  = blockIdx.x * 4 + wave;
    const float4 v = *(const float4*)&x[(size_t)tok * C + lane * 4];
    float s  = v.x + v.y + v.z + v.w;
    float s2 = v.x*v.x + v.y*v.y + v.z*v.z + v.w*v.w;
    #pragma unroll
    for (int o = 32; o > 0; o >>= 1) {
        s  += __shfl_down(s, o);
        s2 += __shfl_down(s2, o);
    }
    if (lane == 0) {
        float m   = s * (1.0f / C);
        float var = s2 * (1.0f / C) - m * m;
        stats[tok * 2]     = m;
        stats[tok * 2 + 1] = rsqrtf(var + EPS);
    }
}

// ---------------- f32 -> bf16 weight convert ----------------
__global__ __launch_bounds__(256)
void cvt_w(const float* __restrict__ in, bf16* __restrict__ o, int n4) {
    int i = blockIdx.x * 256 + threadIdx.x;
    if (i >= n4) return;
    float4 v = *(const float4*)&in[(size_t)i * 4];
    bf16 t4[4] = {__float2bfloat16(v.x), __float2bfloat16(v.y),
                  __float2bfloat16(v.z), __float2bfloat16(v.w)};
    *(uint2*)&o[(size_t)i * 4] = *(const uint2*)t4;
}

// ---------------- vote-embed MLP: w2 in LDS, 1 thread per token ----------
__global__ __launch_bounds__(256)
void vemb_kernel(const float* __restrict__ vote,
                 const float* __restrict__ w1, const float* __restrict__ b1,
                 const float* __restrict__ w2, const float* __restrict__ b2,
                 bf16* __restrict__ vemb) {
    __shared__ float w2s[256][16];
    __shared__ float b2s[256];
    __shared__ float w1s[48], b1s[16];
    const int tid = threadIdx.x;
    {
        const float4* src = (const float4*)(w2 + tid * 16);
        float4* dst = (float4*)&w2s[tid][0];
        dst[0] = src[0]; dst[1] = src[1]; dst[2] = src[2]; dst[3] = src[3];
        b2s[tid] = b2[tid];
        if (tid < 48) w1s[tid] = w1[tid];
        else if (tid < 64) b1s[tid - 48] = b1[tid - 48];
    }
    __syncthreads();

    const int r = blockIdx.x * 256 + tid;
    const int srow = src_row_idx(r);
    const float v0 = vote[(size_t)srow * 3];
    const float v1 = vote[(size_t)srow * 3 + 1];
    const float v2 = vote[(size_t)srow * 3 + 2];
    float hid[16];
    #pragma unroll
    for (int o = 0; o < 16; ++o)
        hid[o] = fmaxf(fmaf(w1s[o*3], v0, fmaf(w1s[o*3+1], v1, fmaf(w1s[o*3+2], v2, b1s[o]))), 0.f);

    bf16* orow = vemb + (size_t)r * 256;
    for (int c0 = 0; c0 < 256; c0 += 8) {
        bf16 t8[8];
        #pragma unroll
        for (int j = 0; j < 8; ++j) {
            const int c = c0 + j;
            float a = b2s[c];
            #pragma unroll
            for (int o = 0; o < 16; ++o) a = fmaf(hid[o], w2s[c][o], a);
            t8[j] = __float2bfloat16(a);
        }
        *(uint4*)&orow[c0] = *(const uint4*)t8;
    }
}

// ---------------- MFMA GEMM: XCD-chunked swizzle + DMA A for bf16 modes ----
// 128x128 tile, BK=64, 4 waves x 64x64. LDS [128][128B] XOR-swizzled.
// Grid 1D = (M/128)*NT; hardware blockIdx round-robins XCDs, so remap
// logical = (bid&7)*(nwg/8) + bid>>3  ->  A-panel-sharing blocks co-locate
// on one XCD (L2 absorbs A re-reads). PROJ/FC2: A staged via global_load_lds
// (inverse-swizzled source); QKV/FC1: A reg-staged with fused LN.
enum { MODE_QKV = 0, MODE_PROJ = 1, MODE_FC1 = 2, MODE_FC2 = 3 };

template <int MODE, int NT>
__global__ __launch_bounds__(256)
void mfma_gemm(const void* __restrict__ Asrc_, const bf16* __restrict__ Wb,
               const float* __restrict__ bias, const float* __restrict__ stats,
               const float* __restrict__ gamma, const float* __restrict__ beta,
               const bf16* __restrict__ vemb, const float* __restrict__ resid,
               void* __restrict__ outp) {
    constexpr int  K  = (MODE == MODE_FC2) ? 1024 : 256;
    constexpr bool LN = (MODE == MODE_QKV) || (MODE == MODE_FC1);
    __shared__ __align__(16) char lds[32768];
    char* ldsA = lds;
    char* ldsB = lds + 16384;

    const int tid  = threadIdx.x;
    const int lane = tid & 63;
    const int wid  = tid >> 6;
    const int wr   = wid >> 1, wc = wid & 1;
    const int lrow = lane & 15, lk = lane >> 4;

    const int cpx = gridDim.x >> 3;                   // nwg always %8==0
    const int lg  = (blockIdx.x & 7) * cpx + (blockIdx.x >> 3);
    const int bx  = lg / NT, by = lg % NT;
    const int mBase = bx * 128, nBase = by * 128;

    const int s_sub = tid >> 3;
    const int chunk = tid & 7;
    const int s_dst = (chunk * 16) ^ ((s_sub & 7) << 4);
    const char* bSrc = (const char*)(Wb + (size_t)(nBase + s_sub) * K) + s_dst;
    const char* aSrcD = (const char*)((const bf16*)Asrc_ + (size_t)(mBase + s_sub) * K) + s_dst;

    int arow[4]; float amean[4], arstd[4];
    if constexpr (LN) {
        #pragma unroll
        for (int r = 0; r < 4; ++r) {
            int row  = mBase + r * 32 + s_sub;
            int srow = (MODE == MODE_QKV) ? src_row_idx(row) : row;
            arow[r] = srow;
            amean[r] = stats[srow * 2];
            arstd[r] = stats[srow * 2 + 1];
        }
    }

    f32x4 acc[4][4] = {};

    for (int t = 0; t < K / 64; ++t) {
        const int k0 = t * 64;
        if (t) __syncthreads();
        #pragma unroll
        for (int r = 0; r < 4; ++r)
            GL2LDS(bSrc + (size_t)r * 64 * K + (size_t)t * 128,
                   ldsB + r * 4096 + wid * 1024);
        if constexpr (!LN) {
            #pragma unroll
            for (int r = 0; r < 4; ++r)
                GL2LDS(aSrcD + (size_t)r * 64 * K + (size_t)t * 128,
                       ldsA + r * 4096 + wid * 1024);
        } else {
            const int kk = k0 + chunk * 8;
            float4 g0  = *(const float4*)&gamma[kk];
            float4 g1v = *(const float4*)&gamma[kk + 4];
            float4 b0  = *(const float4*)&beta[kk];
            float4 b1v = *(const float4*)&beta[kk + 4];
            #pragma unroll
            for (int r = 0; r < 4; ++r) {
                const float* src = (const float*)Asrc_ + (size_t)arow[r] * K + kk;
                float4 v0 = *(const float4*)src;
                float4 v1 = *(const float4*)(src + 4);
                float m = amean[r], sd = arstd[r];
                bf16 tb[8];
                tb[0] = __float2bfloat16((v0.x - m) * sd * g0.x  + b0.x);
                tb[1] = __float2bfloat16((v0.y - m) * sd * g0.y  + b0.y);
                tb[2] = __float2bfloat16((v0.z - m) * sd * g0.z  + b0.z);
                tb[3] = __float2bfloat16((v0.w - m) * sd * g0.w  + b0.w);
                tb[4] = __float2bfloat16((v1.x - m) * sd * g1v.x + b1v.x);
                tb[5] = __float2bfloat16((v1.y - m) * sd * g1v.y + b1v.y);
                tb[6] = __float2bfloat16((v1.z - m) * sd * g1v.z + b1v.z);
                tb[7] = __float2bfloat16((v1.w - m) * sd * g1v.w + b1v.w);
                *(short8*)(ldsA + (r * 32 + s_sub) * 128 + s_dst) = *(const short8*)tb;
            }
        }
        __syncthreads();
        const int sw = (lrow & 7) << 4;
        #pragma unroll
        for (int ks = 0; ks < 2; ++ks) {
            const int kbl = (ks * 64 + lk * 16) ^ sw;
            short8 af[4], bfr[4];
            #pragma unroll
            for (int q = 0; q < 4; ++q) {
                af[q]  = *(const short8*)(ldsA + (wr * 64 + q * 16 + lrow) * 128 + kbl);
                bfr[q] = *(const short8*)(ldsB + (wc * 64 + q * 16 + lrow) * 128 + kbl);
            }
            #pragma unroll
            for (int mi = 0; mi < 4; ++mi)
                #pragma unroll
                for (int ni = 0; ni < 4; ++ni)
                    acc[mi][ni] = __builtin_amdgcn_mfma_f32_16x16x32_bf16(
                        af[mi], bfr[ni], acc[mi][ni], 0, 0, 0);
        }
    }

    const int cB = nBase + wc * 64 + lrow;
    const int rB = mBase + wr * 64 + lk * 4;
    float bs[4];
    #pragma unroll
    for (int ni = 0; ni < 4; ++ni) bs[ni] = bias[cB + ni * 16];
    #pragma unroll
    for (int mi = 0; mi < 4; ++mi) {
        #pragma unroll
        for (int i = 0; i < 4; ++i) {
            const int r = rB + mi * 16 + i;
            const int dst = (MODE == MODE_PROJ) ? src_row_idx(r) : r;
            #pragma unroll
            for (int ni = 0; ni < 4; ++ni) {
                const int c = cB + ni * 16;
                float v = acc[mi][ni][i] + bs[ni];
                if constexpr (MODE == MODE_QKV) {
                    float ve = __bfloat162float(vemb[(size_t)r * 256 + (c & 255)]);
                    v += (c >= 512) ? 2.f * ve : ve;
                    ((bf16*)outp)[(size_t)r * 768 + c] = __float2bfloat16(v);
                } else if constexpr (MODE == MODE_PROJ) {
                    ((float*)outp)[(size_t)dst * 256 + c] =
                        resid[(size_t)dst * 256 + c] + v;
                } else if constexpr (MODE == MODE_FC1) {
                    float gl = 0.5f * v * (1.f + erff(v * 0.70710678118f));
                    ((bf16*)outp)[(size_t)r * 1024 + c] = __float2bfloat16(gl);
                } else {
                    ((float*)outp)[(size_t)r * 256 + c] =
                        resid[(size_t)r * 256 + c] + v;
                }
            }
        }
    }
}

// ---------------- attention v3: head-parallel, zero inner barriers ---------
__global__ __launch_bounds__(256)
void attn_kernel(const bf16* __restrict__ qkv, const float* __restrict__ polar,
                 const float* __restrict__ rw1, const float* __restrict__ rb1,
                 const float* __restrict__ rw2, const float* __restrict__ rb2,
                 const float* __restrict__ tau, const float* __restrict__ mask,
                 bf16* __restrict__ outp) {
    const int w  = blockIdx.x;
    const int wl = w & 255;
    const int t  = threadIdx.x;
    const int lane = t & 63, wid = t >> 6;
    const int l15 = lane & 15, q4 = lane >> 4;
    const size_t wbase = (size_t)w * NWIN;
    const short* qs = (const short*)qkv;

    __shared__ float pwx[NWIN], pwy[NWIN];
    __shared__ float rqn[8][64], rkn[8][64];
    __shared__ float cw1s[32], cb1s[16], cw2s[8][16], rb2s[8], scts[8];
    __shared__ short rpem[8][2401];

    if (t < 98) {
        int n = t >> 1, cix = t & 1;
        int srow = src_row_idx(w * NWIN + n);
        float v = polar[(size_t)srow * 2 + cix];
        if (cix) pwy[n] = v; else pwx[n] = v;
    }
    if (t >= 128 && t < 256) {
        int u = t - 128;
        if (u < 128) cw2s[u >> 4][u & 15] = rw2[u];
    }
    if (t < 32) cw1s[t] = rw1[t];
    else if (t < 48) cb1s[t - 32] = rb1[t - 32];
    else if (t < 56) rb2s[t - 48] = rb2[t - 48];
    else if (t < 64) scts[t - 56] = SCALE / fmaxf(tau[t - 56], 0.01f);

    for (int idx = t; idx < 8 * NWIN; idx += 256) {
        int h = idx / NWIN, n = idx - h * NWIN;
        const bf16* qp = qkv + (wbase + n) * 768 + h * 32;
        float sq = 0, sk = 0;
        #pragma unroll
        for (int c = 0; c < 4; ++c) {
            short8 qv = *(const short8*)(qp + c * 8);
            short8 kv = *(const short8*)(qp + 256 + c * 8);
            #pragma unroll
            for (int j = 0; j < 8; ++j) {
                float qf = bf2f(qv[j]); sq += qf * qf;
                float kf = bf2f(kv[j]); sk += kf * kf;
            }
        }
        rqn[h][n] = rsqrtf(sq);
        rkn[h][n] = rsqrtf(sk);
    }
    __syncthreads();

    for (int e = t; e < NWIN * NWIN; e += 256) {
        int n = e / NWIN, m = e - n * NWIN;
        float dx = pwx[n] - pwx[m], dy = pwy[n] - pwy[m];
        float hid[16];
        #pragma unroll
        for (int o = 0; o < 16; ++o)
            hid[o] = fmaxf(fmaf(cw1s[2*o], dx, fmaf(cw1s[2*o+1], dy, cb1s[o])), 0.f);
        float mv = mask[(size_t)wl * NWIN * NWIN + e];
        #pragma unroll
        for (int h = 0; h < 8; ++h) {
            float a = rb2s[h] + mv;
            #pragma unroll
            for (int o = 0; o < 16; ++o) a = fmaf(hid[o], cw2s[h][o], a);
            rpem[h][e] = f2bfbits(a);
        }
    }
    __syncthreads();

    const short8 z8 = {0,0,0,0,0,0,0,0};
    const int qa  = (q4 & 1) * 2;
    const int sel = q4 >> 1;

    for (int hh = 0; hh < 2; ++hh) {
        const int h = wid + hh * 4;
        const bf16* hbase = qkv + wbase * 768 + h * 32;
        const float sct = scts[h];

        short8 kf[4], qf[4];
        #pragma unroll
        for (int at = 0; at < 4; ++at) {
            int m = at * 16 + l15;
            kf[at] = (m < NWIN) ? *(const short8*)(hbase + (size_t)m * 768 + 256 + q4 * 8) : z8;
        }
        #pragma unroll
        for (int nt = 0; nt < 4; ++nt) {
            int n = nt * 16 + l15;
            qf[nt] = (n < NWIN) ? *(const short8*)(hbase + (size_t)n * 768 + q4 * 8) : z8;
        }
        short8 vb[2][2];
        #pragma unroll
        for (int ks = 0; ks < 2; ++ks)
            #pragma unroll
            for (int ct = 0; ct < 2; ++ct) {
                short tmp[8];
                #pragma unroll
                for (int j = 0; j < 8; ++j) {
                    int m = ks * 32 + q4 * 8 + j;
                    tmp[j] = (m < NWIN)
                        ? qs[(wbase + m) * 768 + 512 + h * 32 + ct * 16 + l15]
                        : (short)0;
                }
                __builtin_memcpy(&vb[ks][ct], tmp, 16);
            }

        u32 pw[4][4][2];
        const f32x4 zf = {0.f, 0.f, 0.f, 0.f};
        #pragma unroll
        for (int nt = 0; nt < 4; ++nt) {
            f32x4 sacc[4];
            #pragma unroll
            for (int at = 0; at < 4; ++at)
                sacc[at] = __builtin_amdgcn_mfma_f32_16x16x32_bf16(kf[at], qf[nt], zf, 0, 0, 0);
            const int n = nt * 16 + l15;
            const float rq = rqn[h][n];
            float pv[4][4];
            #pragma unroll
            for (int at = 0; at < 4; ++at)
                #pragma unroll
                for (int i = 0; i < 4; ++i) {
                    int m = at * 16 + q4 * 4 + i;
                    float val = -1e30f;
                    if (n < NWIN && m < NWIN) {
                        float rr = fminf(rq * rkn[h][m], 1e6f);
                        val = sacc[at][i] * sct * rr + bf2f(rpem[h][n * NWIN + m]);
                    }
                    pv[at][i] = val;
                }
            float mx = -1e30f;
            #pragma unroll
            for (int at = 0; at < 4; ++at)
                #pragma unroll
                for (int i = 0; i < 4; ++i) mx = fmaxf(mx, pv[at][i]);
            mx = fmaxf(mx, __shfl_xor(mx, 16));
            mx = fmaxf(mx, __shfl_xor(mx, 32));
            float sum = 0.f;
            #pragma unroll
            for (int at = 0; at < 4; ++at)
                #pragma unroll
                for (int i = 0; i < 4; ++i) {
                    float ev = __expf(pv[at][i] - mx);
                    pv[at][i] = ev; sum += ev;
                }
            sum += __shfl_xor(sum, 16);
            sum += __shfl_xor(sum, 32);
            const float inv = 1.0f / sum;
            #pragma unroll
            for (int at = 0; at < 4; ++at) {
                pw[nt][at][0] = pack2bf(pv[at][0] * inv, pv[at][1] * inv);
                pw[nt][at][1] = pack2bf(pv[at][2] * inv, pv[at][3] * inv);
            }
        }

        f32x4 o[4][2] = {};
        #pragma unroll
        for (int nt = 0; nt < 4; ++nt) {
            #pragma unroll
            for (int ks = 0; ks < 2; ++ks) {
                u32 wv[4];
                #pragma unroll
                for (int w_ = 0; w_ < 4; ++w_) {
                    int srcl = l15 + (qa + (w_ >> 1)) * 16;
                    u32 lo = (u32)__shfl((int)pw[nt][2 * ks][w_ & 1], srcl);
                    u32 hi = (u32)__shfl((int)pw[nt][2 * ks + 1][w_ & 1], srcl);
                    wv[w_] = sel ? hi : lo;
                }
                short8 pa;
                __builtin_memcpy(&pa, wv, 16);
                #pragma unroll
                for (int ct = 0; ct < 2; ++ct)
                    o[nt][ct] = __builtin_amdgcn_mfma_f32_16x16x32_bf16(pa, vb[ks][ct], o[nt][ct], 0, 0, 0);
            }
        }

        #pragma unroll
        for (int nt = 0; nt < 4; ++nt)
            #pragma unroll
            for (int ct = 0; ct < 2; ++ct)
                #pragma unroll
                for (int i = 0; i < 4; ++i) {
                    int n = nt * 16 + q4 * 4 + i;
                    if (n < NWIN)
                        outp[(wbase + n) * 256 + h * 32 + ct * 16 + l15] =
                            __float2bfloat16(o[nt][ct][i]);
                }
    }
}

// ---------------- launch ----------------
extern "C" void kernel_launch(void* const* d_in, const int* in_sizes, int n_in,
                              void* d_out, int out_size, void* d_ws, size_t ws_size,
                              hipStream_t stream) {
    const float* x     = (const float*)d_in[0];
    const float* mask  = (const float*)d_in[1];
    const float* polar = (const float*)d_in[2];
    const float* vote  = (const float*)d_in[3];
    const float* g1    = (const float*)d_in[4];
    const float* be1   = (const float*)d_in[5];
    const float* wqkv  = (const float*)d_in[6];
    const float* bqkv  = (const float*)d_in[7];
    const float* wproj = (const float*)d_in[8];
    const float* bproj = (const float*)d_in[9];
    const float* tau   = (const float*)d_in[10];
    const float* rw1   = (const float*)d_in[11];
    const float* rb1   = (const float*)d_in[12];
    const float* rw2   = (const float*)d_in[13];
    const float* rb2   = (const float*)d_in[14];
    const float* vw1   = (const float*)d_in[15];
    const float* vb1   = (const float*)d_in[16];
    const float* vw2   = (const float*)d_in[17];
    const float* vb2   = (const float*)d_in[18];
    const float* g2    = (const float*)d_in[19];
    const float* be2   = (const float*)d_in[20];
    const float* fc1w  = (const float*)d_in[21];
    const float* fc1b  = (const float*)d_in[22];
    const float* fc2w  = (const float*)d_in[23];
    const float* fc2b  = (const float*)d_in[24];
    float* out = (float*)d_out;

    // workspace (bytes), total ~105.1 MB (same plan as R4/R6)
    char* base = (char*)d_ws;
    bf16*  qkv     = (bf16*)base;
    bf16*  vemb    = (bf16*)(base + 77070336);
    bf16*  attnout = (bf16*)(base + 77070336);
    bf16*  hbuf    = (bf16*)base;
    bf16*  wqkvb   = (bf16*)(base + 102760448);
    bf16*  wprojb  = wqkvb + 768 * 256;
    bf16*  fc1wb   = wprojb + 256 * 256;
    bf16*  fc2wb   = fc1wb + 1024 * 256;
    float* stats1  = (float*)(base + 104333312);
    float* stats2  = stats1 + 2 * M;

    cvt_w<<<192, 256, 0, stream>>>(wqkv, wqkvb, 768*256/4);
    cvt_w<<<64,  256, 0, stream>>>(wproj, wprojb, 256*256/4);
    cvt_w<<<256, 256, 0, stream>>>(fc1w, fc1wb, 1024*256/4);
    cvt_w<<<256, 256, 0, stream>>>(fc2w, fc2wb, 256*1024/4);

    stats_kernel<<<M / 4, 256, 0, stream>>>(x, stats1);
    vemb_kernel<<<M / 256, 256, 0, stream>>>(vote, vw1, vb1, vw2, vb2, vemb);

    mfma_gemm<MODE_QKV, 6><<<(M / 128) * 6, 256, 0, stream>>>(
        x, wqkvb, bqkv, stats1, g1, be1, vemb, nullptr, qkv);

    attn_kernel<<<BT, 256, 0, stream>>>(qkv, polar, rw1, rb1, rw2, rb2, tau, mask, attnout);

    mfma_gemm<MODE_PROJ, 2><<<(M / 128) * 2, 256, 0, stream>>>(
        attnout, wprojb, bproj, nullptr, nullptr, nullptr, nullptr, x, out);

    stats_kernel<<<M / 4, 256, 0, stream>>>(out, stats2);

    mfma_gemm<MODE_FC1, 8><<<(M / 128) * 8, 256, 0, stream>>>(
        out, fc1wb, fc1b, stats2, g2, be2, nullptr, nullptr, hbuf);

    mfma_gemm<MODE_FC2, 2><<<(M / 128) * 2, 256, 0, stream>>>(
        hbuf, fc2wb, fc2b, nullptr, nullptr, nullptr, nullptr, out, out);
}